// Round 7
// baseline (449.287 us; speedup 1.0000x reference)
//
#include <hip/hip_runtime.h>

#define N_TOKENS 131072
#define DIM 64
#define N_EMBED 1024
#define DECAYF 0.99f
#define OMDF 0.01f
#define EPSF 1e-5f
#define SUM_TPB 128
#define TOK_TILE 128
#define CODE_CHUNK 64
#define NCHUNK (N_EMBED / CODE_CHUNK)
#define MARGIN 0.004f         // 8x the ~5e-4 bf16x3 score error bound
#define FB_BATCH 16
#define FB_BLOCKS 256

// Output layout (floats), reference return order
#define OFF_QST  ((size_t)0)
#define OFF_DIFF ((size_t)8388608)
#define OFF_IND  ((size_t)8388609)
#define OFF_NE   ((size_t)8519681)
#define OFF_NCS  ((size_t)8585217)
#define OFF_NEA  ((size_t)8586241)

// ws: floats f[0] diff_sum, f[1] n_val, f[1026..) es, f[66562..) embedT,
// f[132098..) cnorm; ints at f-idx 133632: cnt_i@0, cursor_i@2048,
// sorted@3072, scode, nflag[0]/done[1] (16-pad), flaglist, bf16 eh_g/el_g.
#define WS_DIFF   0
#define WS_NVAL   1
#define WS_ES     1026
#define WS_ET     66562
#define WS_CNORM  132098
#define WS_IWS    133632

typedef short bfrag8 __attribute__((ext_vector_type(8)));   // 8 bf16 (4 VGPR)
typedef float f32x4  __attribute__((ext_vector_type(4)));

#define GLOAD_LDS16(G, L) \
    __builtin_amdgcn_global_load_lds( \
        (const __attribute__((address_space(1))) void*)(G), \
        (__attribute__((address_space(3))) void*)(L), 16, 0, 0)

__device__ inline unsigned short f2bf(float f) {
    unsigned u = __float_as_uint(f);
    u += 0x7FFFu + ((u >> 16) & 1u);                        // round-to-nearest-even
    return (unsigned short)(u >> 16);
}
__device__ inline float bf2f(unsigned short h) {
    return __uint_as_float(((unsigned)h) << 16);
}
// 8 fp32 -> packed hi/lo bf16 fragments (in registers)
__device__ inline void cvt8(float4 f0, float4 f1, bfrag8* hi, bfrag8* lo) {
    union { bfrag8 v; unsigned u[4]; } H, L;
    unsigned short h0=f2bf(f0.x), h1=f2bf(f0.y), h2=f2bf(f0.z), h3=f2bf(f0.w);
    unsigned short h4=f2bf(f1.x), h5=f2bf(f1.y), h6=f2bf(f1.z), h7=f2bf(f1.w);
    H.u[0]=(unsigned)h0|((unsigned)h1<<16); H.u[1]=(unsigned)h2|((unsigned)h3<<16);
    H.u[2]=(unsigned)h4|((unsigned)h5<<16); H.u[3]=(unsigned)h6|((unsigned)h7<<16);
    L.u[0]=(unsigned)f2bf(f0.x-bf2f(h0))|((unsigned)f2bf(f0.y-bf2f(h1))<<16);
    L.u[1]=(unsigned)f2bf(f0.z-bf2f(h2))|((unsigned)f2bf(f0.w-bf2f(h3))<<16);
    L.u[2]=(unsigned)f2bf(f1.x-bf2f(h4))|((unsigned)f2bf(f1.y-bf2f(h5))<<16);
    L.u[3]=(unsigned)f2bf(f1.z-bf2f(h6))|((unsigned)f2bf(f1.w-bf2f(h7))<<16);
    *hi = H.v; *lo = L.v;
}

// r22 vq_prep: 64x64 LDS tile transpose (pad [64][65]). Old version wrote
// embedT/eh/el at stride-64 (64x write amplification, fully uncoalesced).
// Now: coalesced reads (64 consecutive e per row), coalesced writes (64
// consecutive d per e-row); cnorm computed in-tile with the SAME d-ascending
// fmaf order -> bitwise identical to before. Grid: 16 tile blocks + 1 zeroer.
__global__ __launch_bounds__(256) void vq_prep(
    const float* __restrict__ embed, float* __restrict__ embedT,
    float* __restrict__ cnorm, float* __restrict__ diff_sum,
    int* __restrict__ cnt_i, int* __restrict__ nflag,
    unsigned short* __restrict__ eh_g, unsigned short* __restrict__ el_g)
{
    const int b = blockIdx.x, t = threadIdx.x;
    if (b < 16) {
        __shared__ float tile[64][65];
        const int el_ = t & 63, quad = t >> 6;
        const int eb = b * 64;
#pragma unroll
        for (int p = 0; p < 16; ++p) {
            int d = p * 4 + quad;
            tile[d][el_] = embed[d * N_EMBED + eb + el_];
        }
        __syncthreads();
        if (t < 64) {
            float s = 0.f;
#pragma unroll
            for (int d = 0; d < DIM; ++d) {
                float v = tile[d][t];
                s = fmaf(v, v, s);
            }
            cnorm[eb + t] = s;
        }
#pragma unroll
        for (int p = 0; p < 16; ++p) {
            int e = eb + p * 4 + quad;
            float v = tile[el_][p * 4 + quad];      // d = el_ (lane), 2-way bank alias: free
            int o = e * DIM + el_;
            embedT[o] = v;
            unsigned short h = f2bf(v);
            eh_g[o] = h;
            el_g[o] = f2bf(v - bf2f(h));
        }
    } else {
        for (int i = t; i < N_EMBED; i += 256) cnt_i[i] = 0;
        if (t < 2) diff_sum[t] = 0.f;
        if (t < 2) nflag[t] = 0;           // nflag[0]=count, nflag[1]=done-counter
    }
}

// bf16x3 MFMA distance GEMM.
// r22: EXACT revert to r18 (proven 92.9us local optimum). r19 (4 blocks/CU)
// re-spilled; r20 (counted-vmcnt + J-major) lost MFMA ILP; r21 (interleaved
// scores) exposed MFMA latency to in-order issue (score VALU right after its
// producing MFMA stalls the wave and blocks the next J's independent MFMAs).
// r18's all-MFMAs-then-scores is already optimal: first score op depends on
// an MFMA issued 36 MFMAs earlier.
// LDS swizzle (T2/m201 both-sides): LDS[d]=G[d ^ ((d>>7)&7)<<4] via
// pre-swizzled per-lane GLOBAL source + same XOR on ds_read addr.
__global__ __launch_bounds__(256, 3) void vq_main(
    const float* __restrict__ x, const float* __restrict__ embedT,
    const unsigned short* __restrict__ eh_g, const unsigned short* __restrict__ el_g,
    const float* __restrict__ cnorm, float* __restrict__ out,
    float* __restrict__ diff_sum, int* __restrict__ cnt_i,
    int* __restrict__ nflag, int* __restrict__ flaglist)
{
    __shared__ short lds_B[2][2][CODE_CHUNK * DIM];   // 32 KiB: [buf][hi|lo][64x64]
    // epilogue-only scratch aliased into buf0 (dead after the chunk loop)
    int* bi_l  = (int*)&lds_B[0][0][0];               // 128 i
    int* lhist = bi_l + TOK_TILE;                     // 1024 i (4.5KB total)

    const int t = threadIdx.x;
    const int w = t >> 6, lane = t & 63;
    const int col = lane & 15, q = lane >> 4;
    const int qk = q * 8;

    // swizzled staging source offset: lane*16 with the involution XOR applied
    const int lsw = (lane << 4) ^ (((lane >> 3) & 7) << 4);

#define STAGE(SC, BUF) { \
    const char* ehc_ = (const char*)eh_g + (size_t)(SC) * 8192 + lsw; \
    const char* elc_ = (const char*)el_g + (size_t)(SC) * 8192 + lsw; \
    char* d0_ = (char*)lds_B + (BUF) * 16384; \
    _Pragma("unroll") \
    for (int it_ = 0; it_ < 2; ++it_) { \
        int so_ = (w + it_ * 4) * 1024; \
        GLOAD_LDS16(ehc_ + so_, d0_ + so_); \
        GLOAD_LDS16(elc_ + so_, d0_ + 8192 + so_); \
    } }

    STAGE(0, 0)                                      // issue chunk-0 loads ASAP

    // A-frags: 8 named bfrag8 (KT in {0,1} x I in {0,1}; alloca lesson r10)
    bfrag8 ah0_0, ah0_1, ah1_0, ah1_1;
    bfrag8 al0_0, al0_1, al1_0, al1_1;
    {
        const float* xrb = x + ((size_t)blockIdx.x * TOK_TILE + w * 32 + col) * DIM;
#define MAKE_A(KT, I, AH, AL) { \
        const float* p_ = xrb + (I) * 16 * DIM + (KT) * 32 + qk; \
        cvt8(*(const float4*)p_, *(const float4*)(p_ + 4), &AH, &AL); }
        MAKE_A(0,0,ah0_0,al0_0) MAKE_A(0,1,ah0_1,al0_1)
        MAKE_A(1,0,ah1_0,al1_0) MAKE_A(1,1,ah1_1,al1_1)
#undef MAKE_A
    }

    // per-lane swizzled ds_read byte addrs for kt=0/1; +JJ*2048 folds to imm.
    // lin = (JJ*16+col)*128 + kt*64 + q*16 ; swz XOR = (col&7)<<4 (JJ*16 is
    // 0 mod 8 so the row-XOR is lane-constant). bit6 of base_lin is free ->
    // +64 has no carry into the XOR field; XOR applied after the add.
    const int base_lin = col * 128 + q * 16;
    const int bx = (col & 7) << 4;
    const int a0 = base_lin ^ bx;
    const int a1 = (base_lin + 64) ^ bx;

    float best[8], sec[8];
    int   bidx[8];
#pragma unroll
    for (int s = 0; s < 8; ++s) { best[s] = -3.4e38f; sec[s] = -3.4e38f; bidx[s] = 0; }

    __syncthreads();   // compiler drains vmcnt(0) here -> chunk 0 resident

#define MM3(AH,AL,BH,BL,J) \
    acc[0][J]=__builtin_amdgcn_mfma_f32_16x16x32_bf16(AH##_0,BH,acc[0][J],0,0,0); \
    acc[1][J]=__builtin_amdgcn_mfma_f32_16x16x32_bf16(AH##_1,BH,acc[1][J],0,0,0); \
    acc[0][J]=__builtin_amdgcn_mfma_f32_16x16x32_bf16(AH##_0,BL,acc[0][J],0,0,0); \
    acc[1][J]=__builtin_amdgcn_mfma_f32_16x16x32_bf16(AH##_1,BL,acc[1][J],0,0,0); \
    acc[0][J]=__builtin_amdgcn_mfma_f32_16x16x32_bf16(AL##_0,BH,acc[0][J],0,0,0); \
    acc[1][J]=__builtin_amdgcn_mfma_f32_16x16x32_bf16(AL##_1,BH,acc[1][J],0,0,0);

#define SLOTL(KT, JJ, BUF) { \
    const char* lb_ = (const char*)lds_B + (BUF) * 16384; \
    bfrag8 bh_ = *(const bfrag8*)(lb_ + ((KT) ? a1 : a0) + (JJ) * 2048); \
    bfrag8 bl_ = *(const bfrag8*)(lb_ + 8192 + ((KT) ? a1 : a0) + (JJ) * 2048); \
    MM3(ah##KT, al##KT, bh_, bl_, JJ) }

#define CHUNK_BODY(C, BUF) { \
    if ((C) + 1 < NCHUNK) { STAGE((C) + 1, (BUF) ^ 1) } \
    f32x4 acc[2][4]; \
    _Pragma("unroll") \
    for (int i_ = 0; i_ < 2; ++i_) { \
        _Pragma("unroll") \
        for (int j_ = 0; j_ < 4; ++j_) acc[i_][j_] = (f32x4){0.f, 0.f, 0.f, 0.f}; \
    } \
    SLOTL(0,0,BUF) SLOTL(0,1,BUF) SLOTL(0,2,BUF) SLOTL(0,3,BUF) \
    SLOTL(1,0,BUF) SLOTL(1,1,BUF) SLOTL(1,2,BUF) SLOTL(1,3,BUF) \
    _Pragma("unroll") \
    for (int j = 0; j < 4; ++j) { \
        int code = (C) * CODE_CHUNK + j * 16 + col; \
        float cnj = 0.5f * cnorm[code]; \
        _Pragma("unroll") \
        for (int i = 0; i < 2; ++i) { \
            _Pragma("unroll") \
            for (int r = 0; r < 4; ++r) { \
                float sc = acc[i][j][r] - cnj; \
                int s = i * 4 + r; \
                sec[s] = __builtin_amdgcn_fmed3f(best[s], sec[s], sc); \
                bidx[s] = (sc > best[s]) ? code : bidx[s]; \
                best[s] = fmaxf(best[s], sc); \
            } \
        } \
    } \
    __syncthreads(); }

#pragma unroll 1
    for (int cc = 0; cc < NCHUNK; cc += 2) {
        CHUNK_BODY(cc, 0)
        CHUNK_BODY(cc + 1, 1)
    }
#undef CHUNK_BODY
#undef SLOTL
#undef MM3
#undef STAGE

    // B buffers dead; epilogue scratch aliases buf0. Zero lhist before use.
    for (int i = t; i < N_EMBED; i += 256) lhist[i] = 0;

    // intra-quad butterfly over the 16 code-columns (full code range is
    // wave-local -> result is the per-token global best/sec/idx)
#pragma unroll
    for (int s = 0; s < 8; ++s) {
#pragma unroll
        for (int m = 1; m < 16; m <<= 1) {
            float b2 = __shfl_xor(best[s], m, 64);
            float s2 = __shfl_xor(sec[s],  m, 64);
            int   i2 = __shfl_xor(bidx[s], m, 64);
            float mn = fminf(best[s], b2);
            sec[s]  = fmaxf(fmaxf(sec[s], s2), mn);
            bidx[s] = (b2 > best[s]) ? i2 : bidx[s];
            best[s] = fmaxf(best[s], b2);
        }
    }
    __syncthreads();                                   // lhist zeroed

    if (col == 0) {
#pragma unroll
        for (int i = 0; i < 2; ++i)
#pragma unroll
            for (int r = 0; r < 4; ++r) {
                int s = i * 4 + r;
                int lt = w * 32 + i * 16 + q * 4 + r;
                float B = best[s], S = sec[s];
                int idx = bidx[s];
                bool flag = (B - S) < MARGIN;
                bi_l[lt] = idx | (flag ? 0x10000 : 0);
                int token = blockIdx.x * TOK_TILE + lt;
                out[OFF_IND + token] = (float)idx;     // fallback overwrites flagged
                if (flag) { int p = atomicAdd(&nflag[0], 1); flaglist[p] = token; }
                else atomicAdd(&lhist[idx], 1);
            }
    }
    __syncthreads();

    // quantize + diff for unflagged tokens
    float ds = 0.f;
    {
        const float4* et4 = (const float4*)embedT;
        const float4* xs4 = (const float4*)(x + (size_t)blockIdx.x * TOK_TILE * DIM);
        float4* qst = (float4*)(out + OFF_QST + (size_t)blockIdx.x * TOK_TILE * DIM);
#pragma unroll
        for (int j = 0; j < 8; ++j) {
            int g = j * 256 + t;
            int tok = g >> 4, f = g & 15;
            int bir = bi_l[tok];
            int bi = bir & 0xFFFF;
            float4 qv = et4[bi * 16 + f];
            float4 xv = xs4[g];
            if (!(bir & 0x10000)) {
                qst[g] = qv;
                float ex = qv.x - xv.x, ey = qv.y - xv.y;
                float ez = qv.z - xv.z, ew = qv.w - xv.w;
                ds = fmaf(ex, ex, ds); ds = fmaf(ey, ey, ds);
                ds = fmaf(ez, ez, ds); ds = fmaf(ew, ew, ds);
            }
        }
    }
#pragma unroll
    for (int o = 32; o > 0; o >>= 1) ds += __shfl_down(ds, o, 64);
    if (lane == 0) atomicAdd(diff_sum, ds);

    for (int i = t; i < N_EMBED; i += 256) {
        int cv = lhist[i];
        if (cv) atomicAdd(&cnt_i[i], cv);
    }
}

// Exact fp32 recompute for flagged tokens + (last block) merged prefix-scan /
// EMA / n / diff finalize. r22: ec LDS staging REMOVED -- embedT is 256KB =
// L2-resident (Common-mistake #7: don't stage what cache-fits). Old version
// pushed 512KB through LDS per batch (8 chunks x 2 syncthreads) and read
// ~8MB from LDS per block-batch (LDS-pipe-bound). Direct embedT float4 reads,
// same k4 loop order -> dist bitwise identical, same tie-break. FB_BLOCKS
// 128->256 for batch parallelism.
__global__ __launch_bounds__(256) void vq_fallback(
    const float* __restrict__ x, const float* __restrict__ embedT,
    const float* __restrict__ cnorm, float* __restrict__ out,
    float* __restrict__ diff_sum, int* __restrict__ cnt_i,
    int* __restrict__ nflag, const int* __restrict__ flaglist,
    int* __restrict__ cursor_i, const float* __restrict__ cluster_size,
    float* __restrict__ n_val)
{
    __shared__ float xr[FB_BATCH][68];
    __shared__ float rd[FB_BATCH][16];
    __shared__ int   ri[FB_BATCH][16];
    __shared__ int   win[FB_BATCH];
    __shared__ int   toks[FB_BATCH];
    __shared__ int   lastflag;
    __shared__ int   wtot[4];
    __shared__ float wns[4];

    const int t = threadIdx.x;
    const int nf = nflag[0];

    for (int base = blockIdx.x * FB_BATCH; base < nf; base += gridDim.x * FB_BATCH) {
        __syncthreads();
        if (t < FB_BATCH) toks[t] = (base + t < nf) ? flaglist[base + t] : -1;
        __syncthreads();
        for (int i = t; i < FB_BATCH * 64; i += 256) {
            int tk = i >> 6, d = i & 63;
            int token = toks[tk];
            xr[tk][d] = (token >= 0) ? x[(size_t)token * DIM + d] : 0.f;
        }
        __syncthreads();                               // xr ready
        float bd = 3.4e38f; int be = 0;
        const int tok = t >> 4, l16 = t & 15;
#pragma unroll 1
        for (int ch = 0; ch < 8; ++ch) {
#pragma unroll 1
            for (int cc = 0; cc < 8; ++cc) {
                int ge = ch * 128 + cc * 16 + l16;
                const float4* brow = (const float4*)(embedT + (size_t)ge * DIM);
                float d0 = 0.f, d1 = 0.f, d2 = 0.f, d3 = 0.f;
#pragma unroll
                for (int k4 = 0; k4 < 16; ++k4) {
                    float4 a = *(const float4*)(&xr[tok][k4 << 2]);
                    float4 bv = brow[k4];
                    d0 = fmaf(a.x, bv.x, d0); d1 = fmaf(a.y, bv.y, d1);
                    d2 = fmaf(a.z, bv.z, d2); d3 = fmaf(a.w, bv.w, d3);
                }
                float dist = fmaf(-2.f, (d0 + d1) + (d2 + d3), cnorm[ge]);
                if (dist < bd) { bd = dist; be = ge; }
            }
        }
        rd[tok][l16] = bd; ri[tok][l16] = be;
        __syncthreads();
        if (t < FB_BATCH) {
            float d0 = rd[t][0]; int e0 = ri[t][0];
#pragma unroll
            for (int i = 1; i < 16; ++i) {
                float di = rd[t][i]; int ei = ri[t][i];
                if (di < d0 || (di == d0 && ei < e0)) { d0 = di; e0 = ei; }
            }
            win[t] = e0;
            int token = toks[t];
            if (token >= 0) {
                out[OFF_IND + token] = (float)e0;
                atomicAdd(&cnt_i[e0], 1);
            }
        }
        __syncthreads();
        float ds = 0.f;
        for (int i = t; i < FB_BATCH * 64; i += 256) {
            int tk = i >> 6, d = i & 63;
            int token = toks[tk];
            if (token >= 0) {
                float qv = embedT[(size_t)win[tk] * DIM + d];
                out[OFF_QST + (size_t)token * DIM + d] = qv;
                float e = qv - xr[tk][d];
                ds = fmaf(e, e, ds);
            }
        }
#pragma unroll
        for (int o = 32; o > 0; o >>= 1) ds += __shfl_down(ds, o, 64);
        if ((t & 63) == 0 && ds != 0.f) atomicAdd(diff_sum, ds);
    }

    // ---- last-block: merged vq_start (prefix scan + EMA + n + diff) ----
    __threadfence();                                   // release our updates
    if (t == 0) lastflag = (atomicAdd(&nflag[1], 1) == FB_BLOCKS - 1);
    __syncthreads();
    if (!lastflag) return;
    __threadfence();                                   // acquire others' updates

    const int lane = t & 63, w = t >> 6;
    int base4 = t * 4;
    int c0 = cnt_i[base4], c1 = cnt_i[base4 + 1];
    int c2 = cnt_i[base4 + 2], c3 = cnt_i[base4 + 3];
    int s1 = c0 + c1, s2 = s1 + c2, tot = s2 + c3;

    int inc = tot;
#pragma unroll
    for (int o = 1; o < 64; o <<= 1) {
        int v = __shfl_up(inc, o, 64);
        if (lane >= o) inc += v;
    }
    float ncs0 = cluster_size[base4]     * DECAYF + OMDF * (float)c0;
    float ncs1 = cluster_size[base4 + 1] * DECAYF + OMDF * (float)c1;
    float ncs2 = cluster_size[base4 + 2] * DECAYF + OMDF * (float)c2;
    float ncs3 = cluster_size[base4 + 3] * DECAYF + OMDF * (float)c3;
    out[OFF_NCS + base4]     = ncs0;
    out[OFF_NCS + base4 + 1] = ncs1;
    out[OFF_NCS + base4 + 2] = ncs2;
    out[OFF_NCS + base4 + 3] = ncs3;
    float ns = (ncs0 + ncs1) + (ncs2 + ncs3);
#pragma unroll
    for (int o = 32; o > 0; o >>= 1) ns += __shfl_down(ns, o, 64);
    if (lane == 63) wtot[w] = inc;
    if (lane == 0)  wns[w] = ns;
    __syncthreads();
    int woff = 0;
#pragma unroll
    for (int i = 0; i < 4; ++i) woff += (i < w) ? wtot[i] : 0;
    int eb = woff + inc - tot;                         // exclusive base for base4
    cursor_i[base4]     = eb;
    cursor_i[base4 + 1] = eb + c0;
    cursor_i[base4 + 2] = eb + s1;
    cursor_i[base4 + 3] = eb + s2;
    if (t == 0) {
        float nsum = (wns[0] + wns[1]) + (wns[2] + wns[3]);
        *n_val = nsum;
        out[OFF_DIFF] = *diff_sum / (float)((size_t)N_TOKENS * DIM);
    }
}

__global__ __launch_bounds__(256) void vq_sort(
    const float* __restrict__ out, int* __restrict__ cursor_i,
    int* __restrict__ sorted, int* __restrict__ scode,
    float* __restrict__ es)
{
    __shared__ int lh[N_EMBED];
    __shared__ int lbase[N_EMBED];
    int t = threadIdx.x;
    if (blockIdx.x < 256) es[blockIdx.x * 256 + t] = 0.f;
    for (int i = t; i < N_EMBED; i += 256) lh[i] = 0;
    __syncthreads();
    int tok = blockIdx.x * 256 + t;
    int e = (int)out[OFF_IND + tok];
    int p = atomicAdd(&lh[e], 1);
    __syncthreads();
    for (int i = t; i < N_EMBED; i += 256) {
        int c = lh[i];
        if (c) lbase[i] = atomicAdd(&cursor_i[i], c);
    }
    __syncthreads();
    int pos = lbase[e] + p;
    sorted[pos] = tok;
    scode[pos] = e;
}

// r22: float4 segment-sum. 16 lane-groups x 8 tokens (was 4 waves x 32
// scalar): 4x shorter serial chain, 256B-coalesced token rows. Atomic merge
// order changes (already nondeterministic).
__global__ __launch_bounds__(256) void vq_sum(
    const float* __restrict__ x, const int* __restrict__ sorted,
    const int* __restrict__ scode, float* __restrict__ es)
{
    __shared__ int ltok[SUM_TPB];
    __shared__ int lcode[SUM_TPB];
    const int t = threadIdx.x;
    const int base = blockIdx.x * SUM_TPB;
    if (t < SUM_TPB) {
        ltok[t]  = sorted[base + t];
        lcode[t] = scode[base + t];
    }
    __syncthreads();

    const int g = t >> 4, l4 = (t & 15) << 2;   // group 0..15, dims l4..l4+3
    const int i0 = g * (SUM_TPB / 16);
    int   cur = lcode[i0];
    float ax = 0.f, ay = 0.f, az = 0.f, aw = 0.f;
#pragma unroll
    for (int i = i0; i < i0 + SUM_TPB / 16; ++i) {
        int e = lcode[i];
        if (e != cur) {
            float* p = &es[(size_t)cur * DIM + l4];
            atomicAdd(p, ax); atomicAdd(p + 1, ay);
            atomicAdd(p + 2, az); atomicAdd(p + 3, aw);
            ax = ay = az = aw = 0.f;
            cur = e;
        }
        float4 xv = *(const float4*)(&x[(size_t)ltok[i] * DIM + l4]);
        ax += xv.x; ay += xv.y; az += xv.z; aw += xv.w;
    }
    float* p = &es[(size_t)cur * DIM + l4];
    atomicAdd(p, ax); atomicAdd(p + 1, ay);
    atomicAdd(p + 2, az); atomicAdd(p + 3, aw);
}

__global__ __launch_bounds__(256) void vq_final2(
    const float* __restrict__ embed_avg, const float* __restrict__ es,
    const float* __restrict__ n_val, float* __restrict__ out)
{
    int i = blockIdx.x * 256 + threadIdx.x;
    int e = i & 1023, d = i >> 10;
    float nea = embed_avg[i] * DECAYF + OMDF * es[(size_t)e * DIM + d];
    out[OFF_NEA + i] = nea;
    float ncs = out[OFF_NCS + e];
    float nsum = *n_val;
    float cs = (ncs + EPSF) / (nsum + (float)N_EMBED * EPSF) * nsum;
    out[OFF_NE + i] = nea / cs;
}

extern "C" void kernel_launch(void* const* d_in, const int* in_sizes, int n_in,
                              void* d_out, int out_size, void* d_ws, size_t ws_size,
                              hipStream_t stream)
{
    const float* x            = (const float*)d_in[0];
    const float* embed        = (const float*)d_in[1];
    const float* cluster_size = (const float*)d_in[2];
    const float* embed_avg    = (const float*)d_in[3];
    float* out = (float*)d_out;
    float* ws  = (float*)d_ws;

    float* diff_sum = ws + WS_DIFF;
    float* n_val    = ws + WS_NVAL;
    float* es       = ws + WS_ES;
    float* embedT   = ws + WS_ET;
    float* cnorm    = ws + WS_CNORM;
    int*   iws      = (int*)(ws + WS_IWS);
    int*   cnt_i    = iws;
    int*   cursor_i = iws + 2048;
    int*   sorted   = iws + 3072;
    int*   scode    = sorted + N_TOKENS;
    int*   nflag    = scode + N_TOKENS;                 // [0]=count, [1]=done
    int*   flaglist = nflag + 16;                       // 16-pad keeps bf arrays aligned
    unsigned short* eh_g = (unsigned short*)(flaglist + N_TOKENS);
    unsigned short* el_g = eh_g + N_EMBED * DIM;

    vq_prep<<<17, 256, 0, stream>>>(embed, embedT, cnorm, diff_sum, cnt_i, nflag, eh_g, el_g);
    vq_main<<<N_TOKENS / TOK_TILE, 256, 0, stream>>>(x, embedT, eh_g, el_g, cnorm, out,
                                                     diff_sum, cnt_i, nflag, flaglist);
    vq_fallback<<<FB_BLOCKS, 256, 0, stream>>>(x, embedT, cnorm, out, diff_sum, cnt_i,
                                               nflag, flaglist, cursor_i, cluster_size, n_val);
    vq_sort<<<N_TOKENS / 256, 256, 0, stream>>>(out, cursor_i, sorted, scode, es);
    vq_sum<<<N_TOKENS / SUM_TPB, 256, 0, stream>>>(x, sorted, scode, es);
    vq_final2<<<256, 256, 0, stream>>>(embed_avg, es, n_val, out);
}

// Round 9
// 365.704 us; speedup vs baseline: 1.2286x; 1.2286x over previous
//
#include <hip/hip_runtime.h>

#define N_TOKENS 131072
#define DIM 64
#define N_EMBED 1024
#define DECAYF 0.99f
#define OMDF 0.01f
#define EPSF 1e-5f
#define SUM_TPB 128
#define TOK_TILE 128
#define CODE_CHUNK 64
#define NCHUNK (N_EMBED / CODE_CHUNK)
#define MARGIN 0.004f         // 8x the ~5e-4 bf16x3 score error bound
#define FB_BATCH 16
#define FB_BLOCKS 128

// Output layout (floats), reference return order
#define OFF_QST  ((size_t)0)
#define OFF_DIFF ((size_t)8388608)
#define OFF_IND  ((size_t)8388609)
#define OFF_NE   ((size_t)8519681)
#define OFF_NCS  ((size_t)8585217)
#define OFF_NEA  ((size_t)8586241)

// ws: floats f[0] diff_sum, f[1] n_val, f[1026..) es, f[66562..) embedT,
// f[132098..) cnorm; ints at f-idx 133632: cnt_i@0, cursor_i@2048,
// sorted@3072, scode, nflag[0]/done[1] (16-pad), flaglist, bf16 eh_g/el_g.
#define WS_DIFF   0
#define WS_NVAL   1
#define WS_ES     1026
#define WS_ET     66562
#define WS_CNORM  132098
#define WS_IWS    133632

typedef short bfrag8 __attribute__((ext_vector_type(8)));   // 8 bf16 (4 VGPR)
typedef float f32x4  __attribute__((ext_vector_type(4)));

#define GLOAD_LDS16(G, L) \
    __builtin_amdgcn_global_load_lds( \
        (const __attribute__((address_space(1))) void*)(G), \
        (__attribute__((address_space(3))) void*)(L), 16, 0, 0)

__device__ inline unsigned short f2bf(float f) {
    unsigned u = __float_as_uint(f);
    u += 0x7FFFu + ((u >> 16) & 1u);                        // round-to-nearest-even
    return (unsigned short)(u >> 16);
}
__device__ inline float bf2f(unsigned short h) {
    return __uint_as_float(((unsigned)h) << 16);
}
// 8 fp32 -> packed hi/lo bf16 fragments (in registers)
__device__ inline void cvt8(float4 f0, float4 f1, bfrag8* hi, bfrag8* lo) {
    union { bfrag8 v; unsigned u[4]; } H, L;
    unsigned short h0=f2bf(f0.x), h1=f2bf(f0.y), h2=f2bf(f0.z), h3=f2bf(f0.w);
    unsigned short h4=f2bf(f1.x), h5=f2bf(f1.y), h6=f2bf(f1.z), h7=f2bf(f1.w);
    H.u[0]=(unsigned)h0|((unsigned)h1<<16); H.u[1]=(unsigned)h2|((unsigned)h3<<16);
    H.u[2]=(unsigned)h4|((unsigned)h5<<16); H.u[3]=(unsigned)h6|((unsigned)h7<<16);
    L.u[0]=(unsigned)f2bf(f0.x-bf2f(h0))|((unsigned)f2bf(f0.y-bf2f(h1))<<16);
    L.u[1]=(unsigned)f2bf(f0.z-bf2f(h2))|((unsigned)f2bf(f0.w-bf2f(h3))<<16);
    L.u[2]=(unsigned)f2bf(f1.x-bf2f(h4))|((unsigned)f2bf(f1.y-bf2f(h5))<<16);
    L.u[3]=(unsigned)f2bf(f1.z-bf2f(h6))|((unsigned)f2bf(f1.w-bf2f(h7))<<16);
    *hi = H.v; *lo = L.v;
}

// r24 vq_prep: 64x64 LDS tile transpose (verified passing in r22/r23).
// Coalesced reads AND writes; cnorm computed in-tile with the same
// d-ascending fmaf order. Grid: 16 tile blocks + 1 zeroer.
__global__ __launch_bounds__(256) void vq_prep(
    const float* __restrict__ embed, float* __restrict__ embedT,
    float* __restrict__ cnorm, float* __restrict__ diff_sum,
    int* __restrict__ cnt_i, int* __restrict__ nflag,
    unsigned short* __restrict__ eh_g, unsigned short* __restrict__ el_g)
{
    const int b = blockIdx.x, t = threadIdx.x;
    if (b < 16) {
        __shared__ float tile[64][65];
        const int el_ = t & 63, quad = t >> 6;
        const int eb = b * 64;
#pragma unroll
        for (int p = 0; p < 16; ++p) {
            int d = p * 4 + quad;
            tile[d][el_] = embed[d * N_EMBED + eb + el_];
        }
        __syncthreads();
        if (t < 64) {
            float s = 0.f;
#pragma unroll
            for (int d = 0; d < DIM; ++d) {
                float v = tile[d][t];
                s = fmaf(v, v, s);
            }
            cnorm[eb + t] = s;
        }
#pragma unroll
        for (int p = 0; p < 16; ++p) {
            int e = eb + p * 4 + quad;
            float v = tile[el_][p * 4 + quad];      // d = el_ (lane), 2-way bank alias: free
            int o = e * DIM + el_;
            embedT[o] = v;
            unsigned short h = f2bf(v);
            eh_g[o] = h;
            el_g[o] = f2bf(v - bf2f(h));
        }
    } else {
        for (int i = t; i < N_EMBED; i += 256) cnt_i[i] = 0;
        if (t < 2) diff_sum[t] = 0.f;
        if (t < 2) nflag[t] = 0;           // nflag[0]=count, nflag[1]=done-counter
    }
}

// bf16x3 MFMA distance GEMM.
// r24: r18 structure (proven 92.9us local optimum). r19 (4 blocks/CU)
// re-spilled; r20 (counted-vmcnt + J-major) lost MFMA ILP; r21 (interleaved
// scores) exposed MFMA latency to in-order issue. r18's all-MFMAs-then-scores
// is optimal: first score op depends on an MFMA issued 36 MFMAs earlier.
// LDS swizzle (T2/m201 both-sides): LDS[d]=G[d ^ ((d>>7)&7)<<4] via
// pre-swizzled per-lane GLOBAL source + same XOR on ds_read addr.
__global__ __launch_bounds__(256, 3) void vq_main(
    const float* __restrict__ x, const float* __restrict__ embedT,
    const unsigned short* __restrict__ eh_g, const unsigned short* __restrict__ el_g,
    const float* __restrict__ cnorm, float* __restrict__ out,
    float* __restrict__ diff_sum, int* __restrict__ cnt_i,
    int* __restrict__ nflag, int* __restrict__ flaglist)
{
    __shared__ short lds_B[2][2][CODE_CHUNK * DIM];   // 32 KiB: [buf][hi|lo][64x64]
    // epilogue-only scratch aliased into buf0 (dead after the chunk loop)
    int* bi_l  = (int*)&lds_B[0][0][0];               // 128 i
    int* lhist = bi_l + TOK_TILE;                     // 1024 i (4.5KB total)

    const int t = threadIdx.x;
    const int w = t >> 6, lane = t & 63;
    const int col = lane & 15, q = lane >> 4;
    const int qk = q * 8;

    // swizzled staging source offset: lane*16 with the involution XOR applied
    const int lsw = (lane << 4) ^ (((lane >> 3) & 7) << 4);

#define STAGE(SC, BUF) { \
    const char* ehc_ = (const char*)eh_g + (size_t)(SC) * 8192 + lsw; \
    const char* elc_ = (const char*)el_g + (size_t)(SC) * 8192 + lsw; \
    char* d0_ = (char*)lds_B + (BUF) * 16384; \
    _Pragma("unroll") \
    for (int it_ = 0; it_ < 2; ++it_) { \
        int so_ = (w + it_ * 4) * 1024; \
        GLOAD_LDS16(ehc_ + so_, d0_ + so_); \
        GLOAD_LDS16(elc_ + so_, d0_ + 8192 + so_); \
    } }

    STAGE(0, 0)                                      // issue chunk-0 loads ASAP

    // A-frags: 8 named bfrag8 (KT in {0,1} x I in {0,1}; alloca lesson r10)
    bfrag8 ah0_0, ah0_1, ah1_0, ah1_1;
    bfrag8 al0_0, al0_1, al1_0, al1_1;
    {
        const float* xrb = x + ((size_t)blockIdx.x * TOK_TILE + w * 32 + col) * DIM;
#define MAKE_A(KT, I, AH, AL) { \
        const float* p_ = xrb + (I) * 16 * DIM + (KT) * 32 + qk; \
        cvt8(*(const float4*)p_, *(const float4*)(p_ + 4), &AH, &AL); }
        MAKE_A(0,0,ah0_0,al0_0) MAKE_A(0,1,ah0_1,al0_1)
        MAKE_A(1,0,ah1_0,al1_0) MAKE_A(1,1,ah1_1,al1_1)
#undef MAKE_A
    }

    // per-lane swizzled ds_read byte addrs for kt=0/1; +JJ*2048 folds to imm.
    // lin = (JJ*16+col)*128 + kt*64 + q*16 ; swz XOR = (col&7)<<4 (JJ*16 is
    // 0 mod 8 so the row-XOR is lane-constant). bit6 of base_lin is free ->
    // +64 has no carry into the XOR field; XOR applied after the add.
    const int base_lin = col * 128 + q * 16;
    const int bx = (col & 7) << 4;
    const int a0 = base_lin ^ bx;
    const int a1 = (base_lin + 64) ^ bx;

    float best[8], sec[8];
    int   bidx[8];
#pragma unroll
    for (int s = 0; s < 8; ++s) { best[s] = -3.4e38f; sec[s] = -3.4e38f; bidx[s] = 0; }

    __syncthreads();   // compiler drains vmcnt(0) here -> chunk 0 resident

#define MM3(AH,AL,BH,BL,J) \
    acc[0][J]=__builtin_amdgcn_mfma_f32_16x16x32_bf16(AH##_0,BH,acc[0][J],0,0,0); \
    acc[1][J]=__builtin_amdgcn_mfma_f32_16x16x32_bf16(AH##_1,BH,acc[1][J],0,0,0); \
    acc[0][J]=__builtin_amdgcn_mfma_f32_16x16x32_bf16(AH##_0,BL,acc[0][J],0,0,0); \
    acc[1][J]=__builtin_amdgcn_mfma_f32_16x16x32_bf16(AH##_1,BL,acc[1][J],0,0,0); \
    acc[0][J]=__builtin_amdgcn_mfma_f32_16x16x32_bf16(AL##_0,BH,acc[0][J],0,0,0); \
    acc[1][J]=__builtin_amdgcn_mfma_f32_16x16x32_bf16(AL##_1,BH,acc[1][J],0,0,0);

#define SLOTL(KT, JJ, BUF) { \
    const char* lb_ = (const char*)lds_B + (BUF) * 16384; \
    bfrag8 bh_ = *(const bfrag8*)(lb_ + ((KT) ? a1 : a0) + (JJ) * 2048); \
    bfrag8 bl_ = *(const bfrag8*)(lb_ + 8192 + ((KT) ? a1 : a0) + (JJ) * 2048); \
    MM3(ah##KT, al##KT, bh_, bl_, JJ) }

#define CHUNK_BODY(C, BUF) { \
    if ((C) + 1 < NCHUNK) { STAGE((C) + 1, (BUF) ^ 1) } \
    f32x4 acc[2][4]; \
    _Pragma("unroll") \
    for (int i_ = 0; i_ < 2; ++i_) { \
        _Pragma("unroll") \
        for (int j_ = 0; j_ < 4; ++j_) acc[i_][j_] = (f32x4){0.f, 0.f, 0.f, 0.f}; \
    } \
    SLOTL(0,0,BUF) SLOTL(0,1,BUF) SLOTL(0,2,BUF) SLOTL(0,3,BUF) \
    SLOTL(1,0,BUF) SLOTL(1,1,BUF) SLOTL(1,2,BUF) SLOTL(1,3,BUF) \
    _Pragma("unroll") \
    for (int j = 0; j < 4; ++j) { \
        int code = (C) * CODE_CHUNK + j * 16 + col; \
        float cnj = 0.5f * cnorm[code]; \
        _Pragma("unroll") \
        for (int i = 0; i < 2; ++i) { \
            _Pragma("unroll") \
            for (int r = 0; r < 4; ++r) { \
                float sc = acc[i][j][r] - cnj; \
                int s = i * 4 + r; \
                sec[s] = __builtin_amdgcn_fmed3f(best[s], sec[s], sc); \
                bidx[s] = (sc > best[s]) ? code : bidx[s]; \
                best[s] = fmaxf(best[s], sc); \
            } \
        } \
    } \
    __syncthreads(); }

#pragma unroll 1
    for (int cc = 0; cc < NCHUNK; cc += 2) {
        CHUNK_BODY(cc, 0)
        CHUNK_BODY(cc + 1, 1)
    }
#undef CHUNK_BODY
#undef SLOTL
#undef MM3
#undef STAGE

    // B buffers dead; epilogue scratch aliases buf0. Zero lhist before use.
    for (int i = t; i < N_EMBED; i += 256) lhist[i] = 0;

    // intra-quad butterfly over the 16 code-columns (full code range is
    // wave-local -> result is the per-token global best/sec/idx)
#pragma unroll
    for (int s = 0; s < 8; ++s) {
#pragma unroll
        for (int m = 1; m < 16; m <<= 1) {
            float b2 = __shfl_xor(best[s], m, 64);
            float s2 = __shfl_xor(sec[s],  m, 64);
            int   i2 = __shfl_xor(bidx[s], m, 64);
            float mn = fminf(best[s], b2);
            sec[s]  = fmaxf(fmaxf(sec[s], s2), mn);
            bidx[s] = (b2 > best[s]) ? i2 : bidx[s];
            best[s] = fmaxf(best[s], b2);
        }
    }
    __syncthreads();                                   // lhist zeroed

    if (col == 0) {
#pragma unroll
        for (int i = 0; i < 2; ++i)
#pragma unroll
            for (int r = 0; r < 4; ++r) {
                int s = i * 4 + r;
                int lt = w * 32 + i * 16 + q * 4 + r;
                float B = best[s], S = sec[s];
                int idx = bidx[s];
                bool flag = (B - S) < MARGIN;
                bi_l[lt] = idx | (flag ? 0x10000 : 0);
                int token = blockIdx.x * TOK_TILE + lt;
                out[OFF_IND + token] = (float)idx;     // fallback overwrites flagged
                if (flag) { int p = atomicAdd(&nflag[0], 1); flaglist[p] = token; }
                else atomicAdd(&lhist[idx], 1);
            }
    }
    __syncthreads();

    // quantize + diff for unflagged tokens
    float ds = 0.f;
    {
        const float4* et4 = (const float4*)embedT;
        const float4* xs4 = (const float4*)(x + (size_t)blockIdx.x * TOK_TILE * DIM);
        float4* qst = (float4*)(out + OFF_QST + (size_t)blockIdx.x * TOK_TILE * DIM);
#pragma unroll
        for (int j = 0; j < 8; ++j) {
            int g = j * 256 + t;
            int tok = g >> 4, f = g & 15;
            int bir = bi_l[tok];
            int bi = bir & 0xFFFF;
            float4 qv = et4[bi * 16 + f];
            float4 xv = xs4[g];
            if (!(bir & 0x10000)) {
                qst[g] = qv;
                float ex = qv.x - xv.x, ey = qv.y - xv.y;
                float ez = qv.z - xv.z, ew = qv.w - xv.w;
                ds = fmaf(ex, ex, ds); ds = fmaf(ey, ey, ds);
                ds = fmaf(ez, ez, ds); ds = fmaf(ew, ew, ds);
            }
        }
    }
#pragma unroll
    for (int o = 32; o > 0; o >>= 1) ds += __shfl_down(ds, o, 64);
    if (lane == 0) atomicAdd(diff_sum, ds);

    for (int i = t; i < N_EMBED; i += 256) {
        int cv = lhist[i];
        if (cv) atomicAdd(&cnt_i[i], cv);
    }
}

// Exact fp32 recompute for flagged tokens + (last block) merged prefix-scan /
// EMA / n / diff finalize. ec-LDS-staged version (r21/r23): r22 removed
// staging on the "L2-resident" theory and regressed 168us — direct embedT
// reads are stride-256B UNCOALESCED (dwordx4 splinters into 64 cache-line
// requests, issue-serialized at ~1 wave/SIMD). Cache-fit does NOT excuse
// uncoalesced access; the staged loop reads each chunk coalesced once and
// serves the scattered pattern from LDS.
__global__ __launch_bounds__(256) void vq_fallback(
    const float* __restrict__ x, const float* __restrict__ embedT,
    const float* __restrict__ cnorm, float* __restrict__ out,
    float* __restrict__ diff_sum, int* __restrict__ cnt_i,
    int* __restrict__ nflag, const int* __restrict__ flaglist,
    int* __restrict__ cursor_i, const float* __restrict__ cluster_size,
    float* __restrict__ n_val)
{
    __shared__ float xr[FB_BATCH][68];
    __shared__ float ec[128][68];
    __shared__ float rd[FB_BATCH][16];
    __shared__ int   ri[FB_BATCH][16];
    __shared__ int   win[FB_BATCH];
    __shared__ int   toks[FB_BATCH];
    __shared__ int   lastflag;
    __shared__ int   wtot[4];
    __shared__ float wns[4];

    const int t = threadIdx.x;
    const int nf = nflag[0];

    for (int base = blockIdx.x * FB_BATCH; base < nf; base += gridDim.x * FB_BATCH) {
        __syncthreads();
        if (t < FB_BATCH) toks[t] = (base + t < nf) ? flaglist[base + t] : -1;
        __syncthreads();
        for (int i = t; i < FB_BATCH * 64; i += 256) {
            int tk = i >> 6, d = i & 63;
            int token = toks[tk];
            xr[tk][d] = (token >= 0) ? x[(size_t)token * DIM + d] : 0.f;
        }
        float bd = 3.4e38f; int be = 0;
        const int tok = t >> 4, l16 = t & 15;
        for (int ch = 0; ch < 8; ++ch) {
            __syncthreads();
            {
                const float4* src = (const float4*)(embedT + (size_t)ch * 128 * DIM);
                for (int i = t; i < 2048; i += 256) {
                    int row = i >> 4, kp = (i & 15) << 2;
                    *(float4*)(&ec[row][kp]) = src[i];
                }
            }
            __syncthreads();
#pragma unroll 1
            for (int cc = 0; cc < 8; ++cc) {
                int lc = l16 + cc * 16;
                float d0 = 0.f, d1 = 0.f, d2 = 0.f, d3 = 0.f;
#pragma unroll
                for (int k4 = 0; k4 < 16; ++k4) {
                    float4 a = *(const float4*)(&xr[tok][k4 << 2]);
                    float4 b = *(const float4*)(&ec[lc][k4 << 2]);
                    d0 = fmaf(a.x, b.x, d0); d1 = fmaf(a.y, b.y, d1);
                    d2 = fmaf(a.z, b.z, d2); d3 = fmaf(a.w, b.w, d3);
                }
                int ge = ch * 128 + lc;
                float dist = fmaf(-2.f, (d0 + d1) + (d2 + d3), cnorm[ge]);
                if (dist < bd) { bd = dist; be = ge; }
            }
        }
        rd[tok][l16] = bd; ri[tok][l16] = be;
        __syncthreads();
        if (t < FB_BATCH) {
            float d0 = rd[t][0]; int e0 = ri[t][0];
#pragma unroll
            for (int i = 1; i < 16; ++i) {
                float di = rd[t][i]; int ei = ri[t][i];
                if (di < d0 || (di == d0 && ei < e0)) { d0 = di; e0 = ei; }
            }
            win[t] = e0;
            int token = toks[t];
            if (token >= 0) {
                out[OFF_IND + token] = (float)e0;
                atomicAdd(&cnt_i[e0], 1);
            }
        }
        __syncthreads();
        float ds = 0.f;
        for (int i = t; i < FB_BATCH * 64; i += 256) {
            int tk = i >> 6, d = i & 63;
            int token = toks[tk];
            if (token >= 0) {
                float qv = embedT[(size_t)win[tk] * DIM + d];
                out[OFF_QST + (size_t)token * DIM + d] = qv;
                float e = qv - xr[tk][d];
                ds = fmaf(e, e, ds);
            }
        }
#pragma unroll
        for (int o = 32; o > 0; o >>= 1) ds += __shfl_down(ds, o, 64);
        if ((t & 63) == 0 && ds != 0.f) atomicAdd(diff_sum, ds);
    }

    // ---- last-block: merged vq_start (prefix scan + EMA + n + diff) ----
    __threadfence();                                   // release our updates
    if (t == 0) lastflag = (atomicAdd(&nflag[1], 1) == FB_BLOCKS - 1);
    __syncthreads();
    if (!lastflag) return;
    __threadfence();                                   // acquire others' updates

    const int lane = t & 63, w = t >> 6;
    int base4 = t * 4;
    int c0 = cnt_i[base4], c1 = cnt_i[base4 + 1];
    int c2 = cnt_i[base4 + 2], c3 = cnt_i[base4 + 3];
    int s1 = c0 + c1, s2 = s1 + c2, tot = s2 + c3;

    int inc = tot;
#pragma unroll
    for (int o = 1; o < 64; o <<= 1) {
        int v = __shfl_up(inc, o, 64);
        if (lane >= o) inc += v;
    }
    float ncs0 = cluster_size[base4]     * DECAYF + OMDF * (float)c0;
    float ncs1 = cluster_size[base4 + 1] * DECAYF + OMDF * (float)c1;
    float ncs2 = cluster_size[base4 + 2] * DECAYF + OMDF * (float)c2;
    float ncs3 = cluster_size[base4 + 3] * DECAYF + OMDF * (float)c3;
    out[OFF_NCS + base4]     = ncs0;
    out[OFF_NCS + base4 + 1] = ncs1;
    out[OFF_NCS + base4 + 2] = ncs2;
    out[OFF_NCS + base4 + 3] = ncs3;
    float ns = (ncs0 + ncs1) + (ncs2 + ncs3);
#pragma unroll
    for (int o = 32; o > 0; o >>= 1) ns += __shfl_down(ns, o, 64);
    if (lane == 63) wtot[w] = inc;
    if (lane == 0)  wns[w] = ns;
    __syncthreads();
    int woff = 0;
#pragma unroll
    for (int i = 0; i < 4; ++i) woff += (i < w) ? wtot[i] : 0;
    int eb = woff + inc - tot;                         // exclusive base for base4
    cursor_i[base4]     = eb;
    cursor_i[base4 + 1] = eb + c0;
    cursor_i[base4 + 2] = eb + s1;
    cursor_i[base4 + 3] = eb + s2;
    if (t == 0) {
        float nsum = (wns[0] + wns[1]) + (wns[2] + wns[3]);
        *n_val = nsum;
        out[OFF_DIFF] = *diff_sum / (float)((size_t)N_TOKENS * DIM);
    }
}

__global__ __launch_bounds__(256) void vq_sort(
    const float* __restrict__ out, int* __restrict__ cursor_i,
    int* __restrict__ sorted, int* __restrict__ scode,
    float* __restrict__ es)
{
    __shared__ int lh[N_EMBED];
    __shared__ int lbase[N_EMBED];
    int t = threadIdx.x;
    if (blockIdx.x < 256) es[blockIdx.x * 256 + t] = 0.f;
    for (int i = t; i < N_EMBED; i += 256) lh[i] = 0;
    __syncthreads();
    int tok = blockIdx.x * 256 + t;
    int e = (int)out[OFF_IND + tok];
    int p = atomicAdd(&lh[e], 1);
    __syncthreads();
    for (int i = t; i < N_EMBED; i += 256) {
        int c = lh[i];
        if (c) lbase[i] = atomicAdd(&cursor_i[i], c);
    }
    __syncthreads();
    int pos = lbase[e] + p;
    sorted[pos] = tok;
    scode[pos] = e;
}

// r24: float4 segment-sum (verified passing in r22/r23). 16 lane-groups x 8
// tokens: 4x shorter serial chain, 256B-coalesced token rows.
__global__ __launch_bounds__(256) void vq_sum(
    const float* __restrict__ x, const int* __restrict__ sorted,
    const int* __restrict__ scode, float* __restrict__ es)
{
    __shared__ int ltok[SUM_TPB];
    __shared__ int lcode[SUM_TPB];
    const int t = threadIdx.x;
    const int base = blockIdx.x * SUM_TPB;
    if (t < SUM_TPB) {
        ltok[t]  = sorted[base + t];
        lcode[t] = scode[base + t];
    }
    __syncthreads();

    const int g = t >> 4, l4 = (t & 15) << 2;   // group 0..15, dims l4..l4+3
    const int i0 = g * (SUM_TPB / 16);
    int   cur = lcode[i0];
    float ax = 0.f, ay = 0.f, az = 0.f, aw = 0.f;
#pragma unroll
    for (int i = i0; i < i0 + SUM_TPB / 16; ++i) {
        int e = lcode[i];
        if (e != cur) {
            float* p = &es[(size_t)cur * DIM + l4];
            atomicAdd(p, ax); atomicAdd(p + 1, ay);
            atomicAdd(p + 2, az); atomicAdd(p + 3, aw);
            ax = ay = az = aw = 0.f;
            cur = e;
        }
        float4 xv = *(const float4*)(&x[(size_t)ltok[i] * DIM + l4]);
        ax += xv.x; ay += xv.y; az += xv.z; aw += xv.w;
    }
    float* p = &es[(size_t)cur * DIM + l4];
    atomicAdd(p, ax); atomicAdd(p + 1, ay);
    atomicAdd(p + 2, az); atomicAdd(p + 3, aw);
}

// r24 vq_final2: tile-transpose, GRID FIXED to 16 blocks (r23 launched 256
// blocks -> blocks 16..255 read es OOB and wrote garbage aliasing into the
// NE region: output-3 absmax 4.3e5). Block = 64e x 64d tile: coalesced es
// reads, LDS [64][65] transpose (stride 65 = 1 mod 32 -> conflict-free),
// coalesced embed_avg reads + NEA/NE writes (d-major). Same arithmetic
// expressions -> same values as the original e-fastest version.
__global__ __launch_bounds__(256) void vq_final2(
    const float* __restrict__ embed_avg, const float* __restrict__ es,
    const float* __restrict__ n_val, float* __restrict__ out)
{
    __shared__ float tile[64][65];
    const int b = blockIdx.x, t = threadIdx.x;
    const int el_ = t & 63, quad = t >> 6;
    const int eb = b * 64;
#pragma unroll
    for (int p = 0; p < 16; ++p) {
        int e = p * 4 + quad;
        tile[e][el_] = es[(size_t)(eb + e) * DIM + el_];
    }
    __syncthreads();
    float nsum = *n_val;
    float ncs = out[OFF_NCS + eb + el_];
    float cs = (ncs + EPSF) / (nsum + (float)N_EMBED * EPSF) * nsum;
#pragma unroll
    for (int p = 0; p < 16; ++p) {
        int d = p * 4 + quad;
        int i = d * N_EMBED + eb + el_;
        float nea = embed_avg[i] * DECAYF + OMDF * tile[el_][d];
        out[OFF_NEA + i] = nea;
        out[OFF_NE + i] = nea / cs;
    }
}

extern "C" void kernel_launch(void* const* d_in, const int* in_sizes, int n_in,
                              void* d_out, int out_size, void* d_ws, size_t ws_size,
                              hipStream_t stream)
{
    const float* x            = (const float*)d_in[0];
    const float* embed        = (const float*)d_in[1];
    const float* cluster_size = (const float*)d_in[2];
    const float* embed_avg    = (const float*)d_in[3];
    float* out = (float*)d_out;
    float* ws  = (float*)d_ws;

    float* diff_sum = ws + WS_DIFF;
    float* n_val    = ws + WS_NVAL;
    float* es       = ws + WS_ES;
    float* embedT   = ws + WS_ET;
    float* cnorm    = ws + WS_CNORM;
    int*   iws      = (int*)(ws + WS_IWS);
    int*   cnt_i    = iws;
    int*   cursor_i = iws + 2048;
    int*   sorted   = iws + 3072;
    int*   scode    = sorted + N_TOKENS;
    int*   nflag    = scode + N_TOKENS;                 // [0]=count, [1]=done
    int*   flaglist = nflag + 16;                       // 16-pad keeps bf arrays aligned
    unsigned short* eh_g = (unsigned short*)(flaglist + N_TOKENS);
    unsigned short* el_g = eh_g + N_EMBED * DIM;

    vq_prep<<<17, 256, 0, stream>>>(embed, embedT, cnorm, diff_sum, cnt_i, nflag, eh_g, el_g);
    vq_main<<<N_TOKENS / TOK_TILE, 256, 0, stream>>>(x, embedT, eh_g, el_g, cnorm, out,
                                                     diff_sum, cnt_i, nflag, flaglist);
    vq_fallback<<<FB_BLOCKS, 256, 0, stream>>>(x, embedT, cnorm, out, diff_sum, cnt_i,
                                               nflag, flaglist, cursor_i, cluster_size, n_val);
    vq_sort<<<N_TOKENS / 256, 256, 0, stream>>>(out, cursor_i, sorted, scode, es);
    vq_sum<<<N_TOKENS / SUM_TPB, 256, 0, stream>>>(x, sorted, scode, es);
    vq_final2<<<16, 256, 0, stream>>>(embed_avg, es, n_val, out);
}

// Round 10
// 276.316 us; speedup vs baseline: 1.6260x; 1.3235x over previous
//
#include <hip/hip_runtime.h>

#define N_TOKENS 131072
#define DIM 64
#define N_EMBED 1024
#define DECAYF 0.99f
#define OMDF 0.01f
#define EPSF 1e-5f
#define SUM_TPB 128
#define TOK_TILE 128
#define CODE_CHUNK 64
#define NCHUNK (N_EMBED / CODE_CHUNK)
#define MARGIN 0.004f         // 8x the ~5e-4 bf16x3 score error bound
#define FB_BATCH 16
#define FB_BLOCKS 128

// Output layout (floats), reference return order
#define OFF_QST  ((size_t)0)
#define OFF_DIFF ((size_t)8388608)
#define OFF_IND  ((size_t)8388609)
#define OFF_NE   ((size_t)8519681)
#define OFF_NCS  ((size_t)8585217)
#define OFF_NEA  ((size_t)8586241)

// ws: floats f[0] diff_sum, f[1] n_val, f[1026..) es, f[66562..) embedT,
// f[132098..) cnorm; ints at f-idx 133632: cnt_i@0, cursor_i@2048,
// sorted@3072, scode, nflag[0]/done[1] (16-pad), flaglist, bf16 eh_g/el_g.
#define WS_DIFF   0
#define WS_NVAL   1
#define WS_ES     1026
#define WS_ET     66562
#define WS_CNORM  132098
#define WS_IWS    133632

typedef short bfrag8 __attribute__((ext_vector_type(8)));   // 8 bf16 (4 VGPR)
typedef float f32x4  __attribute__((ext_vector_type(4)));

#define GLOAD_LDS16(G, L) \
    __builtin_amdgcn_global_load_lds( \
        (const __attribute__((address_space(1))) void*)(G), \
        (__attribute__((address_space(3))) void*)(L), 16, 0, 0)

__device__ inline unsigned short f2bf(float f) {
    unsigned u = __float_as_uint(f);
    u += 0x7FFFu + ((u >> 16) & 1u);                        // round-to-nearest-even
    return (unsigned short)(u >> 16);
}
__device__ inline float bf2f(unsigned short h) {
    return __uint_as_float(((unsigned)h) << 16);
}
// 8 fp32 -> packed hi/lo bf16 fragments (in registers)
__device__ inline void cvt8(float4 f0, float4 f1, bfrag8* hi, bfrag8* lo) {
    union { bfrag8 v; unsigned u[4]; } H, L;
    unsigned short h0=f2bf(f0.x), h1=f2bf(f0.y), h2=f2bf(f0.z), h3=f2bf(f0.w);
    unsigned short h4=f2bf(f1.x), h5=f2bf(f1.y), h6=f2bf(f1.z), h7=f2bf(f1.w);
    H.u[0]=(unsigned)h0|((unsigned)h1<<16); H.u[1]=(unsigned)h2|((unsigned)h3<<16);
    H.u[2]=(unsigned)h4|((unsigned)h5<<16); H.u[3]=(unsigned)h6|((unsigned)h7<<16);
    L.u[0]=(unsigned)f2bf(f0.x-bf2f(h0))|((unsigned)f2bf(f0.y-bf2f(h1))<<16);
    L.u[1]=(unsigned)f2bf(f0.z-bf2f(h2))|((unsigned)f2bf(f0.w-bf2f(h3))<<16);
    L.u[2]=(unsigned)f2bf(f1.x-bf2f(h4))|((unsigned)f2bf(f1.y-bf2f(h5))<<16);
    L.u[3]=(unsigned)f2bf(f1.z-bf2f(h6))|((unsigned)f2bf(f1.w-bf2f(h7))<<16);
    *hi = H.v; *lo = L.v;
}

// r25 vq_prep: REVERT to r18's 261-block version. The r22/r23 16-block tile
// rewrite was never counter-indicted as a win; 16 blocks on 256 CUs is
// latency-exposed (94% of the chip idle). The 261-block version spreads the
// stride-64 writes across the whole GPU and never appeared in top-5.
__global__ __launch_bounds__(256) void vq_prep(
    const float* __restrict__ embed, float* __restrict__ embedT,
    float* __restrict__ cnorm, float* __restrict__ diff_sum,
    int* __restrict__ cnt_i, int* __restrict__ nflag,
    unsigned short* __restrict__ eh_g, unsigned short* __restrict__ el_g)
{
    const int b = blockIdx.x, t = threadIdx.x;
    if (b < 256) {
        int i = b * 256 + t;
        int d = i >> 10, e = i & 1023;
        float v = embed[i];
        embedT[e * DIM + d] = v;
        unsigned short h = f2bf(v);
        eh_g[e * DIM + d] = h;
        el_g[e * DIM + d] = f2bf(v - bf2f(h));
    } else if (b < 260) {
        int e = (b - 256) * 256 + t;
        float s = 0.f;
#pragma unroll
        for (int d = 0; d < DIM; ++d) {
            float v = embed[d * N_EMBED + e];
            s = fmaf(v, v, s);
        }
        cnorm[e] = s;
    } else {
        for (int i = t; i < N_EMBED; i += 256) cnt_i[i] = 0;
        if (t < 2) diff_sum[t] = 0.f;
        if (t < 2) nflag[t] = 0;           // nflag[0]=count, nflag[1]=done-counter
    }
}

// bf16x3 MFMA distance GEMM.
// r25: r18 structure (proven 92.9us local optimum). r19 (4 blocks/CU)
// re-spilled; r20 (counted-vmcnt + J-major) lost MFMA ILP; r21 (interleaved
// scores) exposed MFMA latency to in-order issue. r18's all-MFMAs-then-scores
// is optimal: first score op depends on an MFMA issued 36 MFMAs earlier.
// LDS swizzle (T2/m201 both-sides): LDS[d]=G[d ^ ((d>>7)&7)<<4] via
// pre-swizzled per-lane GLOBAL source + same XOR on ds_read addr.
__global__ __launch_bounds__(256, 3) void vq_main(
    const float* __restrict__ x, const float* __restrict__ embedT,
    const unsigned short* __restrict__ eh_g, const unsigned short* __restrict__ el_g,
    const float* __restrict__ cnorm, float* __restrict__ out,
    float* __restrict__ diff_sum, int* __restrict__ cnt_i,
    int* __restrict__ nflag, int* __restrict__ flaglist)
{
    __shared__ short lds_B[2][2][CODE_CHUNK * DIM];   // 32 KiB: [buf][hi|lo][64x64]
    // epilogue-only scratch aliased into buf0 (dead after the chunk loop)
    int* bi_l  = (int*)&lds_B[0][0][0];               // 128 i
    int* lhist = bi_l + TOK_TILE;                     // 1024 i (4.5KB total)

    const int t = threadIdx.x;
    const int w = t >> 6, lane = t & 63;
    const int col = lane & 15, q = lane >> 4;
    const int qk = q * 8;

    // swizzled staging source offset: lane*16 with the involution XOR applied
    const int lsw = (lane << 4) ^ (((lane >> 3) & 7) << 4);

#define STAGE(SC, BUF) { \
    const char* ehc_ = (const char*)eh_g + (size_t)(SC) * 8192 + lsw; \
    const char* elc_ = (const char*)el_g + (size_t)(SC) * 8192 + lsw; \
    char* d0_ = (char*)lds_B + (BUF) * 16384; \
    _Pragma("unroll") \
    for (int it_ = 0; it_ < 2; ++it_) { \
        int so_ = (w + it_ * 4) * 1024; \
        GLOAD_LDS16(ehc_ + so_, d0_ + so_); \
        GLOAD_LDS16(elc_ + so_, d0_ + 8192 + so_); \
    } }

    STAGE(0, 0)                                      // issue chunk-0 loads ASAP

    // A-frags: 8 named bfrag8 (KT in {0,1} x I in {0,1}; alloca lesson r10)
    bfrag8 ah0_0, ah0_1, ah1_0, ah1_1;
    bfrag8 al0_0, al0_1, al1_0, al1_1;
    {
        const float* xrb = x + ((size_t)blockIdx.x * TOK_TILE + w * 32 + col) * DIM;
#define MAKE_A(KT, I, AH, AL) { \
        const float* p_ = xrb + (I) * 16 * DIM + (KT) * 32 + qk; \
        cvt8(*(const float4*)p_, *(const float4*)(p_ + 4), &AH, &AL); }
        MAKE_A(0,0,ah0_0,al0_0) MAKE_A(0,1,ah0_1,al0_1)
        MAKE_A(1,0,ah1_0,al1_0) MAKE_A(1,1,ah1_1,al1_1)
#undef MAKE_A
    }

    // per-lane swizzled ds_read byte addrs for kt=0/1; +JJ*2048 folds to imm.
    // lin = (JJ*16+col)*128 + kt*64 + q*16 ; swz XOR = (col&7)<<4 (JJ*16 is
    // 0 mod 8 so the row-XOR is lane-constant). bit6 of base_lin is free ->
    // +64 has no carry into the XOR field; XOR applied after the add.
    const int base_lin = col * 128 + q * 16;
    const int bx = (col & 7) << 4;
    const int a0 = base_lin ^ bx;
    const int a1 = (base_lin + 64) ^ bx;

    float best[8], sec[8];
    int   bidx[8];
#pragma unroll
    for (int s = 0; s < 8; ++s) { best[s] = -3.4e38f; sec[s] = -3.4e38f; bidx[s] = 0; }

    __syncthreads();   // compiler drains vmcnt(0) here -> chunk 0 resident

#define MM3(AH,AL,BH,BL,J) \
    acc[0][J]=__builtin_amdgcn_mfma_f32_16x16x32_bf16(AH##_0,BH,acc[0][J],0,0,0); \
    acc[1][J]=__builtin_amdgcn_mfma_f32_16x16x32_bf16(AH##_1,BH,acc[1][J],0,0,0); \
    acc[0][J]=__builtin_amdgcn_mfma_f32_16x16x32_bf16(AH##_0,BL,acc[0][J],0,0,0); \
    acc[1][J]=__builtin_amdgcn_mfma_f32_16x16x32_bf16(AH##_1,BL,acc[1][J],0,0,0); \
    acc[0][J]=__builtin_amdgcn_mfma_f32_16x16x32_bf16(AL##_0,BH,acc[0][J],0,0,0); \
    acc[1][J]=__builtin_amdgcn_mfma_f32_16x16x32_bf16(AL##_1,BH,acc[1][J],0,0,0);

#define SLOTL(KT, JJ, BUF) { \
    const char* lb_ = (const char*)lds_B + (BUF) * 16384; \
    bfrag8 bh_ = *(const bfrag8*)(lb_ + ((KT) ? a1 : a0) + (JJ) * 2048); \
    bfrag8 bl_ = *(const bfrag8*)(lb_ + 8192 + ((KT) ? a1 : a0) + (JJ) * 2048); \
    MM3(ah##KT, al##KT, bh_, bl_, JJ) }

#define CHUNK_BODY(C, BUF) { \
    if ((C) + 1 < NCHUNK) { STAGE((C) + 1, (BUF) ^ 1) } \
    f32x4 acc[2][4]; \
    _Pragma("unroll") \
    for (int i_ = 0; i_ < 2; ++i_) { \
        _Pragma("unroll") \
        for (int j_ = 0; j_ < 4; ++j_) acc[i_][j_] = (f32x4){0.f, 0.f, 0.f, 0.f}; \
    } \
    SLOTL(0,0,BUF) SLOTL(0,1,BUF) SLOTL(0,2,BUF) SLOTL(0,3,BUF) \
    SLOTL(1,0,BUF) SLOTL(1,1,BUF) SLOTL(1,2,BUF) SLOTL(1,3,BUF) \
    _Pragma("unroll") \
    for (int j = 0; j < 4; ++j) { \
        int code = (C) * CODE_CHUNK + j * 16 + col; \
        float cnj = 0.5f * cnorm[code]; \
        _Pragma("unroll") \
        for (int i = 0; i < 2; ++i) { \
            _Pragma("unroll") \
            for (int r = 0; r < 4; ++r) { \
                float sc = acc[i][j][r] - cnj; \
                int s = i * 4 + r; \
                sec[s] = __builtin_amdgcn_fmed3f(best[s], sec[s], sc); \
                bidx[s] = (sc > best[s]) ? code : bidx[s]; \
                best[s] = fmaxf(best[s], sc); \
            } \
        } \
    } \
    __syncthreads(); }

#pragma unroll 1
    for (int cc = 0; cc < NCHUNK; cc += 2) {
        CHUNK_BODY(cc, 0)
        CHUNK_BODY(cc + 1, 1)
    }
#undef CHUNK_BODY
#undef SLOTL
#undef MM3
#undef STAGE

    // B buffers dead; epilogue scratch aliases buf0. Zero lhist before use.
    for (int i = t; i < N_EMBED; i += 256) lhist[i] = 0;

    // intra-quad butterfly over the 16 code-columns (full code range is
    // wave-local -> result is the per-token global best/sec/idx)
#pragma unroll
    for (int s = 0; s < 8; ++s) {
#pragma unroll
        for (int m = 1; m < 16; m <<= 1) {
            float b2 = __shfl_xor(best[s], m, 64);
            float s2 = __shfl_xor(sec[s],  m, 64);
            int   i2 = __shfl_xor(bidx[s], m, 64);
            float mn = fminf(best[s], b2);
            sec[s]  = fmaxf(fmaxf(sec[s], s2), mn);
            bidx[s] = (b2 > best[s]) ? i2 : bidx[s];
            best[s] = fmaxf(best[s], b2);
        }
    }
    __syncthreads();                                   // lhist zeroed

    if (col == 0) {
#pragma unroll
        for (int i = 0; i < 2; ++i)
#pragma unroll
            for (int r = 0; r < 4; ++r) {
                int s = i * 4 + r;
                int lt = w * 32 + i * 16 + q * 4 + r;
                float B = best[s], S = sec[s];
                int idx = bidx[s];
                bool flag = (B - S) < MARGIN;
                bi_l[lt] = idx | (flag ? 0x10000 : 0);
                int token = blockIdx.x * TOK_TILE + lt;
                out[OFF_IND + token] = (float)idx;     // fallback overwrites flagged
                if (flag) { int p = atomicAdd(&nflag[0], 1); flaglist[p] = token; }
                else atomicAdd(&lhist[idx], 1);
            }
    }
    __syncthreads();

    // quantize + diff for unflagged tokens
    float ds = 0.f;
    {
        const float4* et4 = (const float4*)embedT;
        const float4* xs4 = (const float4*)(x + (size_t)blockIdx.x * TOK_TILE * DIM);
        float4* qst = (float4*)(out + OFF_QST + (size_t)blockIdx.x * TOK_TILE * DIM);
#pragma unroll
        for (int j = 0; j < 8; ++j) {
            int g = j * 256 + t;
            int tok = g >> 4, f = g & 15;
            int bir = bi_l[tok];
            int bi = bir & 0xFFFF;
            float4 qv = et4[bi * 16 + f];
            float4 xv = xs4[g];
            if (!(bir & 0x10000)) {
                qst[g] = qv;
                float ex = qv.x - xv.x, ey = qv.y - xv.y;
                float ez = qv.z - xv.z, ew = qv.w - xv.w;
                ds = fmaf(ex, ex, ds); ds = fmaf(ey, ey, ds);
                ds = fmaf(ez, ez, ds); ds = fmaf(ew, ew, ds);
            }
        }
    }
#pragma unroll
    for (int o = 32; o > 0; o >>= 1) ds += __shfl_down(ds, o, 64);
    if (lane == 0) atomicAdd(diff_sum, ds);

    for (int i = t; i < N_EMBED; i += 256) {
        int cv = lhist[i];
        if (cv) atomicAdd(&cnt_i[i], cv);
    }
}

// Exact fp32 recompute for flagged tokens + (last block) merged prefix-scan /
// EMA / n / diff finalize. ec-LDS-staged version (r18/r21): r22 removed
// staging on the "L2-resident" theory and regressed 168us — direct embedT
// reads are stride-256B UNCOALESCED. Cache-fit does NOT excuse uncoalesced
// access; the staged loop reads each chunk coalesced once and serves the
// scattered pattern from LDS.
__global__ __launch_bounds__(256) void vq_fallback(
    const float* __restrict__ x, const float* __restrict__ embedT,
    const float* __restrict__ cnorm, float* __restrict__ out,
    float* __restrict__ diff_sum, int* __restrict__ cnt_i,
    int* __restrict__ nflag, const int* __restrict__ flaglist,
    int* __restrict__ cursor_i, const float* __restrict__ cluster_size,
    float* __restrict__ n_val)
{
    __shared__ float xr[FB_BATCH][68];
    __shared__ float ec[128][68];
    __shared__ float rd[FB_BATCH][16];
    __shared__ int   ri[FB_BATCH][16];
    __shared__ int   win[FB_BATCH];
    __shared__ int   toks[FB_BATCH];
    __shared__ int   lastflag;
    __shared__ int   wtot[4];
    __shared__ float wns[4];

    const int t = threadIdx.x;
    const int nf = nflag[0];

    for (int base = blockIdx.x * FB_BATCH; base < nf; base += gridDim.x * FB_BATCH) {
        __syncthreads();
        if (t < FB_BATCH) toks[t] = (base + t < nf) ? flaglist[base + t] : -1;
        __syncthreads();
        for (int i = t; i < FB_BATCH * 64; i += 256) {
            int tk = i >> 6, d = i & 63;
            int token = toks[tk];
            xr[tk][d] = (token >= 0) ? x[(size_t)token * DIM + d] : 0.f;
        }
        float bd = 3.4e38f; int be = 0;
        const int tok = t >> 4, l16 = t & 15;
        for (int ch = 0; ch < 8; ++ch) {
            __syncthreads();
            {
                const float4* src = (const float4*)(embedT + (size_t)ch * 128 * DIM);
                for (int i = t; i < 2048; i += 256) {
                    int row = i >> 4, kp = (i & 15) << 2;
                    *(float4*)(&ec[row][kp]) = src[i];
                }
            }
            __syncthreads();
#pragma unroll 1
            for (int cc = 0; cc < 8; ++cc) {
                int lc = l16 + cc * 16;
                float d0 = 0.f, d1 = 0.f, d2 = 0.f, d3 = 0.f;
#pragma unroll
                for (int k4 = 0; k4 < 16; ++k4) {
                    float4 a = *(const float4*)(&xr[tok][k4 << 2]);
                    float4 b = *(const float4*)(&ec[lc][k4 << 2]);
                    d0 = fmaf(a.x, b.x, d0); d1 = fmaf(a.y, b.y, d1);
                    d2 = fmaf(a.z, b.z, d2); d3 = fmaf(a.w, b.w, d3);
                }
                int ge = ch * 128 + lc;
                float dist = fmaf(-2.f, (d0 + d1) + (d2 + d3), cnorm[ge]);
                if (dist < bd) { bd = dist; be = ge; }
            }
        }
        rd[tok][l16] = bd; ri[tok][l16] = be;
        __syncthreads();
        if (t < FB_BATCH) {
            float d0 = rd[t][0]; int e0 = ri[t][0];
#pragma unroll
            for (int i = 1; i < 16; ++i) {
                float di = rd[t][i]; int ei = ri[t][i];
                if (di < d0 || (di == d0 && ei < e0)) { d0 = di; e0 = ei; }
            }
            win[t] = e0;
            int token = toks[t];
            if (token >= 0) {
                out[OFF_IND + token] = (float)e0;
                atomicAdd(&cnt_i[e0], 1);
            }
        }
        __syncthreads();
        float ds = 0.f;
        for (int i = t; i < FB_BATCH * 64; i += 256) {
            int tk = i >> 6, d = i & 63;
            int token = toks[tk];
            if (token >= 0) {
                float qv = embedT[(size_t)win[tk] * DIM + d];
                out[OFF_QST + (size_t)token * DIM + d] = qv;
                float e = qv - xr[tk][d];
                ds = fmaf(e, e, ds);
            }
        }
#pragma unroll
    for (int o = 32; o > 0; o >>= 1) ds += __shfl_down(ds, o, 64);
        if ((t & 63) == 0 && ds != 0.f) atomicAdd(diff_sum, ds);
    }

    // ---- last-block: merged vq_start (prefix scan + EMA + n + diff) ----
    __threadfence();                                   // release our updates
    if (t == 0) lastflag = (atomicAdd(&nflag[1], 1) == FB_BLOCKS - 1);
    __syncthreads();
    if (!lastflag) return;
    __threadfence();                                   // acquire others' updates

    const int lane = t & 63, w = t >> 6;
    int base4 = t * 4;
    int c0 = cnt_i[base4], c1 = cnt_i[base4 + 1];
    int c2 = cnt_i[base4 + 2], c3 = cnt_i[base4 + 3];
    int s1 = c0 + c1, s2 = s1 + c2, tot = s2 + c3;

    int inc = tot;
#pragma unroll
    for (int o = 1; o < 64; o <<= 1) {
        int v = __shfl_up(inc, o, 64);
        if (lane >= o) inc += v;
    }
    float ncs0 = cluster_size[base4]     * DECAYF + OMDF * (float)c0;
    float ncs1 = cluster_size[base4 + 1] * DECAYF + OMDF * (float)c1;
    float ncs2 = cluster_size[base4 + 2] * DECAYF + OMDF * (float)c2;
    float ncs3 = cluster_size[base4 + 3] * DECAYF + OMDF * (float)c3;
    out[OFF_NCS + base4]     = ncs0;
    out[OFF_NCS + base4 + 1] = ncs1;
    out[OFF_NCS + base4 + 2] = ncs2;
    out[OFF_NCS + base4 + 3] = ncs3;
    float ns = (ncs0 + ncs1) + (ncs2 + ncs3);
#pragma unroll
    for (int o = 32; o > 0; o >>= 1) ns += __shfl_down(ns, o, 64);
    if (lane == 63) wtot[w] = inc;
    if (lane == 0)  wns[w] = ns;
    __syncthreads();
    int woff = 0;
#pragma unroll
    for (int i = 0; i < 4; ++i) woff += (i < w) ? wtot[i] : 0;
    int eb = woff + inc - tot;                         // exclusive base for base4
    cursor_i[base4]     = eb;
    cursor_i[base4 + 1] = eb + c0;
    cursor_i[base4 + 2] = eb + s1;
    cursor_i[base4 + 3] = eb + s2;
    if (t == 0) {
        float nsum = (wns[0] + wns[1]) + (wns[2] + wns[3]);
        *n_val = nsum;
        out[OFF_DIFF] = *diff_sum / (float)((size_t)N_TOKENS * DIM);
    }
}

__global__ __launch_bounds__(256) void vq_sort(
    const float* __restrict__ out, int* __restrict__ cursor_i,
    int* __restrict__ sorted, int* __restrict__ scode,
    float* __restrict__ es)
{
    __shared__ int lh[N_EMBED];
    __shared__ int lbase[N_EMBED];
    int t = threadIdx.x;
    if (blockIdx.x < 256) es[blockIdx.x * 256 + t] = 0.f;
    for (int i = t; i < N_EMBED; i += 256) lh[i] = 0;
    __syncthreads();
    int tok = blockIdx.x * 256 + t;
    int e = (int)out[OFF_IND + tok];
    int p = atomicAdd(&lh[e], 1);
    __syncthreads();
    for (int i = t; i < N_EMBED; i += 256) {
        int c = lh[i];
        if (c) lbase[i] = atomicAdd(&cursor_i[i], c);
    }
    __syncthreads();
    int pos = lbase[e] + p;
    sorted[pos] = tok;
    scode[pos] = e;
}

// r25 vq_sum: two-phase. The r22 float4 version (116us, VALUBusy 0.38%,
// 329 GB/s) fused the serial segment-scan with the random-row gather: 16B
// chunked loads with conditional atomics interleaved -> no load pipelining,
// plus 4x segment flushes (16 groups vs 4 waves). Phase 1 gathers all 128
// token rows into LDS with ZERO inter-load dependencies (wave-uniform ltok
// broadcast -> 32 independent coalesced 256B row loads, deeply in flight;
// 4 blocks/CU x 16 waves). Phase 2 = r18's proven 4-wave x 32-token segment
// scan reading LDS (~120cyc) with the same flush pattern (1 atomic/lane/
// segment, 64-lane rows). Per-(wave,d) summation order identical to r18's
// scalar version -> es identical up to atomic commit order.
__global__ __launch_bounds__(256) void vq_sum(
    const float* __restrict__ x, const int* __restrict__ sorted,
    const int* __restrict__ scode, float* __restrict__ es)
{
    __shared__ int   ltok[SUM_TPB];
    __shared__ int   lcode[SUM_TPB];
    __shared__ float xs[SUM_TPB][64];                  // 32 KB
    const int t = threadIdx.x;
    const int base = blockIdx.x * SUM_TPB;
    if (t < SUM_TPB) {
        ltok[t]  = sorted[base + t];
        lcode[t] = scode[base + t];
    }
    __syncthreads();

    // phase 1: gather 128 rows -> LDS (wave w loads rows w, w+4, w+8, ...)
    {
        float4* xs4 = (float4*)&xs[0][0];
        const float4* x4 = (const float4*)x;
#pragma unroll
        for (int i = t; i < SUM_TPB * 16; i += 256) {
            int tk = i >> 4, f = i & 15;
            xs4[tk * 16 + f] = x4[(size_t)ltok[tk] * 16 + f];
        }
    }
    __syncthreads();

    // phase 2: per-wave serial segment scan from LDS (r18 structure)
    const int w = t >> 6, d = t & 63;
    const int i0 = w * (SUM_TPB / 4);
    int   cur = lcode[i0];
    float acc = 0.f;
#pragma unroll 4
    for (int i = i0; i < i0 + SUM_TPB / 4; ++i) {
        int e = lcode[i];
        if (e != cur) {
            atomicAdd(&es[(size_t)cur * DIM + d], acc);
            acc = 0.f;
            cur = e;
        }
        acc += xs[i][d];
    }
    atomicAdd(&es[(size_t)cur * DIM + d], acc);
}

// r25 vq_final2: REVERT to r18's 256-block flat version (1 elem/thread,
// 65536 threads of TLP hide the stride-256B es gather; never appeared in
// top-5). The r23/r24 16-block tile version starved the chip of blocks.
__global__ __launch_bounds__(256) void vq_final2(
    const float* __restrict__ embed_avg, const float* __restrict__ es,
    const float* __restrict__ n_val, float* __restrict__ out)
{
    int i = blockIdx.x * 256 + threadIdx.x;
    int e = i & 1023, d = i >> 10;
    float nea = embed_avg[i] * DECAYF + OMDF * es[(size_t)e * DIM + d];
    out[OFF_NEA + i] = nea;
    float ncs = out[OFF_NCS + e];
    float nsum = *n_val;
    float cs = (ncs + EPSF) / (nsum + (float)N_EMBED * EPSF) * nsum;
    out[OFF_NE + i] = nea / cs;
}

extern "C" void kernel_launch(void* const* d_in, const int* in_sizes, int n_in,
                              void* d_out, int out_size, void* d_ws, size_t ws_size,
                              hipStream_t stream)
{
    const float* x            = (const float*)d_in[0];
    const float* embed        = (const float*)d_in[1];
    const float* cluster_size = (const float*)d_in[2];
    const float* embed_avg    = (const float*)d_in[3];
    float* out = (float*)d_out;
    float* ws  = (float*)d_ws;

    float* diff_sum = ws + WS_DIFF;
    float* n_val    = ws + WS_NVAL;
    float* es       = ws + WS_ES;
    float* embedT   = ws + WS_ET;
    float* cnorm    = ws + WS_CNORM;
    int*   iws      = (int*)(ws + WS_IWS);
    int*   cnt_i    = iws;
    int*   cursor_i = iws + 2048;
    int*   sorted   = iws + 3072;
    int*   scode    = sorted + N_TOKENS;
    int*   nflag    = scode + N_TOKENS;                 // [0]=count, [1]=done
    int*   flaglist = nflag + 16;                       // 16-pad keeps bf arrays aligned
    unsigned short* eh_g = (unsigned short*)(flaglist + N_TOKENS);
    unsigned short* el_g = eh_g + N_EMBED * DIM;

    vq_prep<<<261, 256, 0, stream>>>(embed, embedT, cnorm, diff_sum, cnt_i, nflag, eh_g, el_g);
    vq_main<<<N_TOKENS / TOK_TILE, 256, 0, stream>>>(x, embedT, eh_g, el_g, cnorm, out,
                                                     diff_sum, cnt_i, nflag, flaglist);
    vq_fallback<<<FB_BLOCKS, 256, 0, stream>>>(x, embedT, cnorm, out, diff_sum, cnt_i,
                                               nflag, flaglist, cursor_i, cluster_size, n_val);
    vq_sort<<<N_TOKENS / 256, 256, 0, stream>>>(out, cursor_i, sorted, scode, es);
    vq_sum<<<N_TOKENS / SUM_TPB, 256, 0, stream>>>(x, sorted, scode, es);
    vq_final2<<<256, 256, 0, stream>>>(embed_avg, es, n_val, out);
}

// Round 11
// 270.711 us; speedup vs baseline: 1.6597x; 1.0207x over previous
//
#include <hip/hip_runtime.h>

#define N_TOKENS 131072
#define DIM 64
#define N_EMBED 1024
#define DECAYF 0.99f
#define OMDF 0.01f
#define EPSF 1e-5f
#define SUM_TPB 128
#define TOK_TILE 128
#define CODE_CHUNK 64
#define NCHUNK (N_EMBED / CODE_CHUNK)
#define MARGIN 0.004f         // 8x the ~5e-4 bf16x3 score error bound
#define FB_BATCH 16
#define FB_BLOCKS 128

// Output layout (floats), reference return order
#define OFF_QST  ((size_t)0)
#define OFF_DIFF ((size_t)8388608)
#define OFF_IND  ((size_t)8388609)
#define OFF_NE   ((size_t)8519681)
#define OFF_NCS  ((size_t)8585217)
#define OFF_NEA  ((size_t)8586241)

// ws: floats f[0] diff_sum, f[1] n_val, f[1026..) es, f[66562..) embedT,
// f[132098..) cnorm; ints at f-idx 133632: cnt_i@0, cursor_i@2048,
// sorted@3072 (packed (e<<17)|tok), scode (unused), nflag[0]/done[1]
// (16-pad), flaglist, bf16 eh_g/el_g.
#define WS_DIFF   0
#define WS_NVAL   1
#define WS_ES     1026
#define WS_ET     66562
#define WS_CNORM  132098
#define WS_IWS    133632

typedef short bfrag8 __attribute__((ext_vector_type(8)));   // 8 bf16 (4 VGPR)
typedef float f32x4  __attribute__((ext_vector_type(4)));

#define GLOAD_LDS16(G, L) \
    __builtin_amdgcn_global_load_lds( \
        (const __attribute__((address_space(1))) void*)(G), \
        (__attribute__((address_space(3))) void*)(L), 16, 0, 0)

__device__ inline unsigned short f2bf(float f) {
    unsigned u = __float_as_uint(f);
    u += 0x7FFFu + ((u >> 16) & 1u);                        // round-to-nearest-even
    return (unsigned short)(u >> 16);
}
__device__ inline float bf2f(unsigned short h) {
    return __uint_as_float(((unsigned)h) << 16);
}
// 8 fp32 -> packed hi/lo bf16 fragments (in registers)
__device__ inline void cvt8(float4 f0, float4 f1, bfrag8* hi, bfrag8* lo) {
    union { bfrag8 v; unsigned u[4]; } H, L;
    unsigned short h0=f2bf(f0.x), h1=f2bf(f0.y), h2=f2bf(f0.z), h3=f2bf(f0.w);
    unsigned short h4=f2bf(f1.x), h5=f2bf(f1.y), h6=f2bf(f1.z), h7=f2bf(f1.w);
    H.u[0]=(unsigned)h0|((unsigned)h1<<16); H.u[1]=(unsigned)h2|((unsigned)h3<<16);
    H.u[2]=(unsigned)h4|((unsigned)h5<<16); H.u[3]=(unsigned)h6|((unsigned)h7<<16);
    L.u[0]=(unsigned)f2bf(f0.x-bf2f(h0))|((unsigned)f2bf(f0.y-bf2f(h1))<<16);
    L.u[1]=(unsigned)f2bf(f0.z-bf2f(h2))|((unsigned)f2bf(f0.w-bf2f(h3))<<16);
    L.u[2]=(unsigned)f2bf(f1.x-bf2f(h4))|((unsigned)f2bf(f1.y-bf2f(h5))<<16);
    L.u[3]=(unsigned)f2bf(f1.z-bf2f(h6))|((unsigned)f2bf(f1.w-bf2f(h7))<<16);
    *hi = H.v; *lo = L.v;
}

// r26 vq_prep: write-coalesced transpose. Old b<256 path wrote embedT/eh/el
// at e*64+d with e fastest: 4B/2B stores at 256B/128B stride, and each 64B
// output sector collects writes from ~64 DIFFERENT blocks across 8 XCDs ->
// dirty-line ping-pong through non-coherent L2s. Now block b owns e-rows
// 4b..4b+3: lane d reads embed[d][e] (scattered in d, but embed = 256KB
// L2-resident -> scattered READS don't ping-pong) and writes all three
// output rows fully coalesced. Per-element values identical -> bitwise-same
// outputs. cnorm blocks (256..259) unchanged: same serial d-ascending fmaf
// order -> bitwise identical.
__global__ __launch_bounds__(256) void vq_prep(
    const float* __restrict__ embed, float* __restrict__ embedT,
    float* __restrict__ cnorm, float* __restrict__ diff_sum,
    int* __restrict__ cnt_i, int* __restrict__ nflag,
    unsigned short* __restrict__ eh_g, unsigned short* __restrict__ el_g)
{
    const int b = blockIdx.x, t = threadIdx.x;
    if (b < 256) {
        int e = b * 4 + (t >> 6), d = t & 63;
        float v = embed[d * N_EMBED + e];
        int o = e * DIM + d;
        embedT[o] = v;
        unsigned short h = f2bf(v);
        eh_g[o] = h;
        el_g[o] = f2bf(v - bf2f(h));
    } else if (b < 260) {
        int e = (b - 256) * 256 + t;
        float s = 0.f;
#pragma unroll
        for (int d = 0; d < DIM; ++d) {
            float v = embed[d * N_EMBED + e];
            s = fmaf(v, v, s);
        }
        cnorm[e] = s;
    } else {
        for (int i = t; i < N_EMBED; i += 256) cnt_i[i] = 0;
        if (t < 2) diff_sum[t] = 0.f;
        if (t < 2) nflag[t] = 0;           // nflag[0]=count, nflag[1]=done-counter
    }
}

// bf16x3 MFMA distance GEMM.
// r26: r18 structure (proven 92.9us local optimum, re-verified r25 at 91).
// r19 (4 blocks/CU) re-spilled; r20 (counted-vmcnt + J-major) lost MFMA ILP;
// r21 (interleaved scores) exposed MFMA latency to in-order issue. r18's
// all-MFMAs-then-scores is optimal: first score op depends on an MFMA
// issued 36 MFMAs earlier.
// LDS swizzle (T2/m201 both-sides): LDS[d]=G[d ^ ((d>>7)&7)<<4] via
// pre-swizzled per-lane GLOBAL source + same XOR on ds_read addr.
__global__ __launch_bounds__(256, 3) void vq_main(
    const float* __restrict__ x, const float* __restrict__ embedT,
    const unsigned short* __restrict__ eh_g, const unsigned short* __restrict__ el_g,
    const float* __restrict__ cnorm, float* __restrict__ out,
    float* __restrict__ diff_sum, int* __restrict__ cnt_i,
    int* __restrict__ nflag, int* __restrict__ flaglist)
{
    __shared__ short lds_B[2][2][CODE_CHUNK * DIM];   // 32 KiB: [buf][hi|lo][64x64]
    // epilogue-only scratch aliased into buf0 (dead after the chunk loop)
    int* bi_l  = (int*)&lds_B[0][0][0];               // 128 i
    int* lhist = bi_l + TOK_TILE;                     // 1024 i (4.5KB total)

    const int t = threadIdx.x;
    const int w = t >> 6, lane = t & 63;
    const int col = lane & 15, q = lane >> 4;
    const int qk = q * 8;

    // swizzled staging source offset: lane*16 with the involution XOR applied
    const int lsw = (lane << 4) ^ (((lane >> 3) & 7) << 4);

#define STAGE(SC, BUF) { \
    const char* ehc_ = (const char*)eh_g + (size_t)(SC) * 8192 + lsw; \
    const char* elc_ = (const char*)el_g + (size_t)(SC) * 8192 + lsw; \
    char* d0_ = (char*)lds_B + (BUF) * 16384; \
    _Pragma("unroll") \
    for (int it_ = 0; it_ < 2; ++it_) { \
        int so_ = (w + it_ * 4) * 1024; \
        GLOAD_LDS16(ehc_ + so_, d0_ + so_); \
        GLOAD_LDS16(elc_ + so_, d0_ + 8192 + so_); \
    } }

    STAGE(0, 0)                                      // issue chunk-0 loads ASAP

    // A-frags: 8 named bfrag8 (KT in {0,1} x I in {0,1}; alloca lesson r10)
    bfrag8 ah0_0, ah0_1, ah1_0, ah1_1;
    bfrag8 al0_0, al0_1, al1_0, al1_1;
    {
        const float* xrb = x + ((size_t)blockIdx.x * TOK_TILE + w * 32 + col) * DIM;
#define MAKE_A(KT, I, AH, AL) { \
        const float* p_ = xrb + (I) * 16 * DIM + (KT) * 32 + qk; \
        cvt8(*(const float4*)p_, *(const float4*)(p_ + 4), &AH, &AL); }
        MAKE_A(0,0,ah0_0,al0_0) MAKE_A(0,1,ah0_1,al0_1)
        MAKE_A(1,0,ah1_0,al1_0) MAKE_A(1,1,ah1_1,al1_1)
#undef MAKE_A
    }

    // per-lane swizzled ds_read byte addrs for kt=0/1; +JJ*2048 folds to imm.
    // lin = (JJ*16+col)*128 + kt*64 + q*16 ; swz XOR = (col&7)<<4 (JJ*16 is
    // 0 mod 8 so the row-XOR is lane-constant). bit6 of base_lin is free ->
    // +64 has no carry into the XOR field; XOR applied after the add.
    const int base_lin = col * 128 + q * 16;
    const int bx = (col & 7) << 4;
    const int a0 = base_lin ^ bx;
    const int a1 = (base_lin + 64) ^ bx;

    float best[8], sec[8];
    int   bidx[8];
#pragma unroll
    for (int s = 0; s < 8; ++s) { best[s] = -3.4e38f; sec[s] = -3.4e38f; bidx[s] = 0; }

    __syncthreads();   // compiler drains vmcnt(0) here -> chunk 0 resident

#define MM3(AH,AL,BH,BL,J) \
    acc[0][J]=__builtin_amdgcn_mfma_f32_16x16x32_bf16(AH##_0,BH,acc[0][J],0,0,0); \
    acc[1][J]=__builtin_amdgcn_mfma_f32_16x16x32_bf16(AH##_1,BH,acc[1][J],0,0,0); \
    acc[0][J]=__builtin_amdgcn_mfma_f32_16x16x32_bf16(AH##_0,BL,acc[0][J],0,0,0); \
    acc[1][J]=__builtin_amdgcn_mfma_f32_16x16x32_bf16(AH##_1,BL,acc[1][J],0,0,0); \
    acc[0][J]=__builtin_amdgcn_mfma_f32_16x16x32_bf16(AL##_0,BH,acc[0][J],0,0,0); \
    acc[1][J]=__builtin_amdgcn_mfma_f32_16x16x32_bf16(AL##_1,BH,acc[1][J],0,0,0);

#define SLOTL(KT, JJ, BUF) { \
    const char* lb_ = (const char*)lds_B + (BUF) * 16384; \
    bfrag8 bh_ = *(const bfrag8*)(lb_ + ((KT) ? a1 : a0) + (JJ) * 2048); \
    bfrag8 bl_ = *(const bfrag8*)(lb_ + 8192 + ((KT) ? a1 : a0) + (JJ) * 2048); \
    MM3(ah##KT, al##KT, bh_, bl_, JJ) }

#define CHUNK_BODY(C, BUF) { \
    if ((C) + 1 < NCHUNK) { STAGE((C) + 1, (BUF) ^ 1) } \
    f32x4 acc[2][4]; \
    _Pragma("unroll") \
    for (int i_ = 0; i_ < 2; ++i_) { \
        _Pragma("unroll") \
        for (int j_ = 0; j_ < 4; ++j_) acc[i_][j_] = (f32x4){0.f, 0.f, 0.f, 0.f}; \
    } \
    SLOTL(0,0,BUF) SLOTL(0,1,BUF) SLOTL(0,2,BUF) SLOTL(0,3,BUF) \
    SLOTL(1,0,BUF) SLOTL(1,1,BUF) SLOTL(1,2,BUF) SLOTL(1,3,BUF) \
    _Pragma("unroll") \
    for (int j = 0; j < 4; ++j) { \
        int code = (C) * CODE_CHUNK + j * 16 + col; \
        float cnj = 0.5f * cnorm[code]; \
        _Pragma("unroll") \
        for (int i = 0; i < 2; ++i) { \
            _Pragma("unroll") \
            for (int r = 0; r < 4; ++r) { \
                float sc = acc[i][j][r] - cnj; \
                int s = i * 4 + r; \
                sec[s] = __builtin_amdgcn_fmed3f(best[s], sec[s], sc); \
                bidx[s] = (sc > best[s]) ? code : bidx[s]; \
                best[s] = fmaxf(best[s], sc); \
            } \
        } \
    } \
    __syncthreads(); }

#pragma unroll 1
    for (int cc = 0; cc < NCHUNK; cc += 2) {
        CHUNK_BODY(cc, 0)
        CHUNK_BODY(cc + 1, 1)
    }
#undef CHUNK_BODY
#undef SLOTL
#undef MM3
#undef STAGE

    // B buffers dead; epilogue scratch aliases buf0. Zero lhist before use.
    for (int i = t; i < N_EMBED; i += 256) lhist[i] = 0;

    // intra-quad butterfly over the 16 code-columns (full code range is
    // wave-local -> result is the per-token global best/sec/idx)
#pragma unroll
    for (int s = 0; s < 8; ++s) {
#pragma unroll
        for (int m = 1; m < 16; m <<= 1) {
            float b2 = __shfl_xor(best[s], m, 64);
            float s2 = __shfl_xor(sec[s],  m, 64);
            int   i2 = __shfl_xor(bidx[s], m, 64);
            float mn = fminf(best[s], b2);
            sec[s]  = fmaxf(fmaxf(sec[s], s2), mn);
            bidx[s] = (b2 > best[s]) ? i2 : bidx[s];
            best[s] = fmaxf(best[s], b2);
        }
    }
    __syncthreads();                                   // lhist zeroed

    if (col == 0) {
#pragma unroll
        for (int i = 0; i < 2; ++i)
#pragma unroll
            for (int r = 0; r < 4; ++r) {
                int s = i * 4 + r;
                int lt = w * 32 + i * 16 + q * 4 + r;
                float B = best[s], S = sec[s];
                int idx = bidx[s];
                bool flag = (B - S) < MARGIN;
                bi_l[lt] = idx | (flag ? 0x10000 : 0);
                int token = blockIdx.x * TOK_TILE + lt;
                out[OFF_IND + token] = (float)idx;     // fallback overwrites flagged
                if (flag) { int p = atomicAdd(&nflag[0], 1); flaglist[p] = token; }
                else atomicAdd(&lhist[idx], 1);
            }
    }
    __syncthreads();

    // quantize + diff for unflagged tokens
    float ds = 0.f;
    {
        const float4* et4 = (const float4*)embedT;
        const float4* xs4 = (const float4*)(x + (size_t)blockIdx.x * TOK_TILE * DIM);
        float4* qst = (float4*)(out + OFF_QST + (size_t)blockIdx.x * TOK_TILE * DIM);
#pragma unroll
        for (int j = 0; j < 8; ++j) {
            int g = j * 256 + t;
            int tok = g >> 4, f = g & 15;
            int bir = bi_l[tok];
            int bi = bir & 0xFFFF;
            float4 qv = et4[bi * 16 + f];
            float4 xv = xs4[g];
            if (!(bir & 0x10000)) {
                qst[g] = qv;
                float ex = qv.x - xv.x, ey = qv.y - xv.y;
                float ez = qv.z - xv.z, ew = qv.w - xv.w;
                ds = fmaf(ex, ex, ds); ds = fmaf(ey, ey, ds);
                ds = fmaf(ez, ez, ds); ds = fmaf(ew, ew, ds);
            }
        }
    }
#pragma unroll
    for (int o = 32; o > 0; o >>= 1) ds += __shfl_down(ds, o, 64);
    if (lane == 0) atomicAdd(diff_sum, ds);

    for (int i = t; i < N_EMBED; i += 256) {
        int cv = lhist[i];
        if (cv) atomicAdd(&cnt_i[i], cv);
    }
}

// Exact fp32 recompute for flagged tokens + (last block) merged prefix-scan /
// EMA / n / diff finalize. ec-LDS-staged version (r18/r21): r22 removed
// staging on the "L2-resident" theory and regressed 168us — direct embedT
// reads are stride-256B UNCOALESCED. Cache-fit does NOT excuse uncoalesced
// access; the staged loop reads each chunk coalesced once and serves the
// scattered pattern from LDS.
__global__ __launch_bounds__(256) void vq_fallback(
    const float* __restrict__ x, const float* __restrict__ embedT,
    const float* __restrict__ cnorm, float* __restrict__ out,
    float* __restrict__ diff_sum, int* __restrict__ cnt_i,
    int* __restrict__ nflag, const int* __restrict__ flaglist,
    int* __restrict__ cursor_i, const float* __restrict__ cluster_size,
    float* __restrict__ n_val)
{
    __shared__ float xr[FB_BATCH][68];
    __shared__ float ec[128][68];
    __shared__ float rd[FB_BATCH][16];
    __shared__ int   ri[FB_BATCH][16];
    __shared__ int   win[FB_BATCH];
    __shared__ int   toks[FB_BATCH];
    __shared__ int   lastflag;
    __shared__ int   wtot[4];
    __shared__ float wns[4];

    const int t = threadIdx.x;
    const int nf = nflag[0];

    for (int base = blockIdx.x * FB_BATCH; base < nf; base += gridDim.x * FB_BATCH) {
        __syncthreads();
        if (t < FB_BATCH) toks[t] = (base + t < nf) ? flaglist[base + t] : -1;
        __syncthreads();
        for (int i = t; i < FB_BATCH * 64; i += 256) {
            int tk = i >> 6, d = i & 63;
            int token = toks[tk];
            xr[tk][d] = (token >= 0) ? x[(size_t)token * DIM + d] : 0.f;
        }
        float bd = 3.4e38f; int be = 0;
        const int tok = t >> 4, l16 = t & 15;
        for (int ch = 0; ch < 8; ++ch) {
            __syncthreads();
            {
                const float4* src = (const float4*)(embedT + (size_t)ch * 128 * DIM);
                for (int i = t; i < 2048; i += 256) {
                    int row = i >> 4, kp = (i & 15) << 2;
                    *(float4*)(&ec[row][kp]) = src[i];
                }
            }
            __syncthreads();
#pragma unroll 1
            for (int cc = 0; cc < 8; ++cc) {
                int lc = l16 + cc * 16;
                float d0 = 0.f, d1 = 0.f, d2 = 0.f, d3 = 0.f;
#pragma unroll
                for (int k4 = 0; k4 < 16; ++k4) {
                    float4 a = *(const float4*)(&xr[tok][k4 << 2]);
                    float4 b = *(const float4*)(&ec[lc][k4 << 2]);
                    d0 = fmaf(a.x, b.x, d0); d1 = fmaf(a.y, b.y, d1);
                    d2 = fmaf(a.z, b.z, d2); d3 = fmaf(a.w, b.w, d3);
                }
                int ge = ch * 128 + lc;
                float dist = fmaf(-2.f, (d0 + d1) + (d2 + d3), cnorm[ge]);
                if (dist < bd) { bd = dist; be = ge; }
            }
        }
        rd[tok][l16] = bd; ri[tok][l16] = be;
        __syncthreads();
        if (t < FB_BATCH) {
            float d0 = rd[t][0]; int e0 = ri[t][0];
#pragma unroll
            for (int i = 1; i < 16; ++i) {
                float di = rd[t][i]; int ei = ri[t][i];
                if (di < d0 || (di == d0 && ei < e0)) { d0 = di; e0 = ei; }
            }
            win[t] = e0;
            int token = toks[t];
            if (token >= 0) {
                out[OFF_IND + token] = (float)e0;
                atomicAdd(&cnt_i[e0], 1);
            }
        }
        __syncthreads();
        float ds = 0.f;
        for (int i = t; i < FB_BATCH * 64; i += 256) {
            int tk = i >> 6, d = i & 63;
            int token = toks[tk];
            if (token >= 0) {
                float qv = embedT[(size_t)win[tk] * DIM + d];
                out[OFF_QST + (size_t)token * DIM + d] = qv;
                float e = qv - xr[tk][d];
                ds = fmaf(e, e, ds);
            }
        }
#pragma unroll
    for (int o = 32; o > 0; o >>= 1) ds += __shfl_down(ds, o, 64);
        if ((t & 63) == 0 && ds != 0.f) atomicAdd(diff_sum, ds);
    }

    // ---- last-block: merged vq_start (prefix scan + EMA + n + diff) ----
    __threadfence();                                   // release our updates
    if (t == 0) lastflag = (atomicAdd(&nflag[1], 1) == FB_BLOCKS - 1);
    __syncthreads();
    if (!lastflag) return;
    __threadfence();                                   // acquire others' updates

    const int lane = t & 63, w = t >> 6;
    int base4 = t * 4;
    int c0 = cnt_i[base4], c1 = cnt_i[base4 + 1];
    int c2 = cnt_i[base4 + 2], c3 = cnt_i[base4 + 3];
    int s1 = c0 + c1, s2 = s1 + c2, tot = s2 + c3;

    int inc = tot;
#pragma unroll
    for (int o = 1; o < 64; o <<= 1) {
        int v = __shfl_up(inc, o, 64);
        if (lane >= o) inc += v;
    }
    float ncs0 = cluster_size[base4]     * DECAYF + OMDF * (float)c0;
    float ncs1 = cluster_size[base4 + 1] * DECAYF + OMDF * (float)c1;
    float ncs2 = cluster_size[base4 + 2] * DECAYF + OMDF * (float)c2;
    float ncs3 = cluster_size[base4 + 3] * DECAYF + OMDF * (float)c3;
    out[OFF_NCS + base4]     = ncs0;
    out[OFF_NCS + base4 + 1] = ncs1;
    out[OFF_NCS + base4 + 2] = ncs2;
    out[OFF_NCS + base4 + 3] = ncs3;
    float ns = (ncs0 + ncs1) + (ncs2 + ncs3);
#pragma unroll
    for (int o = 32; o > 0; o >>= 1) ns += __shfl_down(ns, o, 64);
    if (lane == 63) wtot[w] = inc;
    if (lane == 0)  wns[w] = ns;
    __syncthreads();
    int woff = 0;
#pragma unroll
    for (int i = 0; i < 4; ++i) woff += (i < w) ? wtot[i] : 0;
    int eb = woff + inc - tot;                         // exclusive base for base4
    cursor_i[base4]     = eb;
    cursor_i[base4 + 1] = eb + c0;
    cursor_i[base4 + 2] = eb + s1;
    cursor_i[base4 + 3] = eb + s2;
    if (t == 0) {
        float nsum = (wns[0] + wns[1]) + (wns[2] + wns[3]);
        *n_val = nsum;
        out[OFF_DIFF] = *diff_sum / (float)((size_t)N_TOKENS * DIM);
    }
}

// r26 vq_sort: pack (code,token) into ONE int -> one scattered 4B store per
// token instead of two (the counting-sort scatter is transaction-bound;
// halving store count halves it). tok = 17 bits, e = 10 bits: (e<<17)|tok.
__global__ __launch_bounds__(256) void vq_sort(
    const float* __restrict__ out, int* __restrict__ cursor_i,
    int* __restrict__ sorted, float* __restrict__ es)
{
    __shared__ int lh[N_EMBED];
    __shared__ int lbase[N_EMBED];
    int t = threadIdx.x;
    if (blockIdx.x < 256) es[blockIdx.x * 256 + t] = 0.f;
    for (int i = t; i < N_EMBED; i += 256) lh[i] = 0;
    __syncthreads();
    int tok = blockIdx.x * 256 + t;
    int e = (int)out[OFF_IND + tok];
    int p = atomicAdd(&lh[e], 1);
    __syncthreads();
    for (int i = t; i < N_EMBED; i += 256) {
        int c = lh[i];
        if (c) lbase[i] = atomicAdd(&cursor_i[i], c);
    }
    __syncthreads();
    int pos = lbase[e] + p;
    sorted[pos] = (e << 17) | tok;
}

// r26 vq_sum: two-phase (r25, vq_sum 116->out-of-top5), reading the packed
// (e<<17)|tok array (halves index loads). Phase 1 gathers all 128 token
// rows into LDS with zero inter-load dependencies (coalesced 256B rows,
// deeply pipelined); phase 2 = the proven 4-wave x 32-token serial segment
// scan from LDS with the same flush pattern. Per-(wave,d) summation order
// unchanged -> es identical up to atomic commit order.
__global__ __launch_bounds__(256) void vq_sum(
    const float* __restrict__ x, const int* __restrict__ sorted,
    float* __restrict__ es)
{
    __shared__ int   ltok[SUM_TPB];
    __shared__ int   lcode[SUM_TPB];
    __shared__ float xs[SUM_TPB][64];                  // 32 KB
    const int t = threadIdx.x;
    const int base = blockIdx.x * SUM_TPB;
    if (t < SUM_TPB) {
        int v = sorted[base + t];
        ltok[t]  = v & 0x1FFFF;
        lcode[t] = v >> 17;
    }
    __syncthreads();

    // phase 1: gather 128 rows -> LDS (independent coalesced row loads)
    {
        float4* xs4 = (float4*)&xs[0][0];
        const float4* x4 = (const float4*)x;
#pragma unroll
        for (int i = t; i < SUM_TPB * 16; i += 256) {
            int tk = i >> 4, f = i & 15;
            xs4[tk * 16 + f] = x4[(size_t)ltok[tk] * 16 + f];
        }
    }
    __syncthreads();

    // phase 2: per-wave serial segment scan from LDS (r18 structure)
    const int w = t >> 6, d = t & 63;
    const int i0 = w * (SUM_TPB / 4);
    int   cur = lcode[i0];
    float acc = 0.f;
#pragma unroll 4
    for (int i = i0; i < i0 + SUM_TPB / 4; ++i) {
        int e = lcode[i];
        if (e != cur) {
            atomicAdd(&es[(size_t)cur * DIM + d], acc);
            acc = 0.f;
            cur = e;
        }
        acc += xs[i][d];
    }
    atomicAdd(&es[(size_t)cur * DIM + d], acc);
}

// r26 vq_final2: r18's 256-block flat version (1 elem/thread, 65536 threads
// of TLP hide the stride-256B es gather; never appeared in top-5).
__global__ __launch_bounds__(256) void vq_final2(
    const float* __restrict__ embed_avg, const float* __restrict__ es,
    const float* __restrict__ n_val, float* __restrict__ out)
{
    int i = blockIdx.x * 256 + threadIdx.x;
    int e = i & 1023, d = i >> 10;
    float nea = embed_avg[i] * DECAYF + OMDF * es[(size_t)e * DIM + d];
    out[OFF_NEA + i] = nea;
    float ncs = out[OFF_NCS + e];
    float nsum = *n_val;
    float cs = (ncs + EPSF) / (nsum + (float)N_EMBED * EPSF) * nsum;
    out[OFF_NE + i] = nea / cs;
}

extern "C" void kernel_launch(void* const* d_in, const int* in_sizes, int n_in,
                              void* d_out, int out_size, void* d_ws, size_t ws_size,
                              hipStream_t stream)
{
    const float* x            = (const float*)d_in[0];
    const float* embed        = (const float*)d_in[1];
    const float* cluster_size = (const float*)d_in[2];
    const float* embed_avg    = (const float*)d_in[3];
    float* out = (float*)d_out;
    float* ws  = (float*)d_ws;

    float* diff_sum = ws + WS_DIFF;
    float* n_val    = ws + WS_NVAL;
    float* es       = ws + WS_ES;
    float* embedT   = ws + WS_ET;
    float* cnorm    = ws + WS_CNORM;
    int*   iws      = (int*)(ws + WS_IWS);
    int*   cnt_i    = iws;
    int*   cursor_i = iws + 2048;
    int*   sorted   = iws + 3072;                       // packed (e<<17)|tok
    int*   scode    = sorted + N_TOKENS;                // unused (layout kept)
    int*   nflag    = scode + N_TOKENS;                 // [0]=count, [1]=done
    int*   flaglist = nflag + 16;                       // 16-pad keeps bf arrays aligned
    unsigned short* eh_g = (unsigned short*)(flaglist + N_TOKENS);
    unsigned short* el_g = eh_g + N_EMBED * DIM;

    vq_prep<<<261, 256, 0, stream>>>(embed, embedT, cnorm, diff_sum, cnt_i, nflag, eh_g, el_g);
    vq_main<<<N_TOKENS / TOK_TILE, 256, 0, stream>>>(x, embedT, eh_g, el_g, cnorm, out,
                                                     diff_sum, cnt_i, nflag, flaglist);
    vq_fallback<<<FB_BLOCKS, 256, 0, stream>>>(x, embedT, cnorm, out, diff_sum, cnt_i,
                                               nflag, flaglist, cursor_i, cluster_size, n_val);
    vq_sort<<<N_TOKENS / 256, 256, 0, stream>>>(out, cursor_i, sorted, es);
    vq_sum<<<N_TOKENS / SUM_TPB, 256, 0, stream>>>(x, sorted, es);
    vq_final2<<<256, 256, 0, stream>>>(embed_avg, es, n_val, out);
}